// Round 17
// baseline (206.955 us; speedup 1.0000x reference)
//
#include <hip/hip_runtime.h>
#include <math.h>

#define M_TOK 25600   // 25 images * 1024 tokens

typedef __attribute__((ext_vector_type(8))) short bf16x8;
typedef __attribute__((ext_vector_type(4))) float f32x4;
typedef __attribute__((ext_vector_type(4))) int   i32x4;
typedef __attribute__((ext_vector_type(2))) int   i32x2;

__device__ __forceinline__ unsigned short f2b(float x) {
    unsigned u = __builtin_bit_cast(unsigned, x);
    return (unsigned short)((u + 0x7fffu + ((u >> 16) & 1u)) >> 16);
}
__device__ __forceinline__ float b2f(unsigned short h) {
    unsigned u = ((unsigned)h) << 16;
    return __builtin_bit_cast(float, u);
}
__device__ __forceinline__ unsigned cvtpk(float lo, float hi) {
    unsigned r;
    asm("v_cvt_pk_bf16_f32 %0, %1, %2" : "=v"(r) : "v"(lo), "v"(hi));
    return r;
}

// ---------------------------------------------------------------------------
// Merged prep (r14 verbatim): weight fp32->bf16 + dw-weight transposes.
// ---------------------------------------------------------------------------
__global__ __launch_bounds__(256) void prep_k(const float* __restrict__ s0, const float* __restrict__ s1,
                                              const float* __restrict__ s2, const float* __restrict__ s3,
                                              const float* __restrict__ s4, const float* __restrict__ s5,
                                              const float* __restrict__ qw, const float* __restrict__ fw,
                                              short* __restrict__ dst,
                                              float* __restrict__ wqT, float* __restrict__ wgT) {
    int i = blockIdx.x * 256 + threadIdx.x;      // < 297320
    if (i >= 297320) return;
    if (i < 287744) {
        if (i < 81920) {
            int r = i % 640, d = i / 640;        // k = tap*64 + cc (tap-major)
            int tap = r >> 6, cc = r & 63;
            dst[i] = (tap < 9) ? (short)f2b(s0[(d * 64 + cc) * 9 + tap]) : (short)0;
            return;
        }
        if (i >= 234496 && i < 279552) {         // ffn_out padded [128][352]
            int l = i - 234496;
            int row = l / 352, col = l % 352;
            dst[i] = (col < 340) ? (short)f2b(s4[row * 340 + col]) : (short)0;
            return;
        }
        const float* s; int off;
        if      (i < 131072) { s = s1; off = i - 81920; }
        else if (i < 147456) { s = s2; off = i - 131072; }
        else if (i < 234496) { s = s3; off = i - 147456; }
        else                 { s = s5; off = i - 279552; }
        dst[i] = (short)f2b(s[off]);
        return;
    }
    int j = i - 287744;                          // < 9576
    if (j < 3456) {
        int tap = j / 384, c = j % 384;
        wqT[j] = qw[c * 9 + tap];
    } else {
        int k = j - 3456;
        int tap = k / 680, c = k % 680;
        wgT[k] = fw[c * 9 + tap];
    }
}

// ---------------------------------------------------------------------------
// bf16 MFMA GEMM, 64x64 tile (r16 verbatim, PROVEN).
// ---------------------------------------------------------------------------
template <bool ADD, bool TROUT, bool AF32>
__global__ __launch_bounds__(256) void mm64_k(const void* __restrict__ Avp,
                                              const short* __restrict__ W,
                                              float* __restrict__ outp,
                                              int M, int N, int K) {
    __shared__ __align__(16) short As[2][64 * 40];
    __shared__ __align__(16) short Bs[2][64 * 40];
    const int tid = threadIdx.x;
    const int bm = blockIdx.x * 64;
    const int bn = blockIdx.y * 64;
    const int w = tid >> 6, lane = tid & 63;
    const int h = lane >> 4, l15 = lane & 15;
    const int wm = (w >> 1) * 32, wn = (w & 1) * 32;

    const int row = tid >> 2, c4 = tid & 3;
    const int gnW = bn + row;

    f32x4 acc[2][2];
#pragma unroll
    for (int i = 0; i < 2; ++i)
#pragma unroll
        for (int j = 0; j < 2; ++j) acc[i][j] = (f32x4){0.f, 0.f, 0.f, 0.f};

    short av[8], wv[8];

    auto ldA = [&](int k0, short* tmp) {
        int gk = k0 + c4 * 8;
        size_t abase = (size_t)(bm + row) * K + gk;
        if (AF32) {
            const float* ap = (const float*)Avp + abase;
            float4 va = *(const float4*)ap;
            float4 vb = *(const float4*)(ap + 4);
            tmp[0] = (short)f2b(va.x); tmp[1] = (short)f2b(va.y);
            tmp[2] = (short)f2b(va.z); tmp[3] = (short)f2b(va.w);
            tmp[4] = (short)f2b(vb.x); tmp[5] = (short)f2b(vb.y);
            tmp[6] = (short)f2b(vb.z); tmp[7] = (short)f2b(vb.w);
        } else {
            const short* ap = (const short*)Avp + abase;
            i32x2 a = *(const i32x2*)ap;
            i32x2 b = *(const i32x2*)(ap + 4);
            *(i32x2*)&tmp[0] = a; *(i32x2*)&tmp[4] = b;
        }
    };
    auto ldW = [&](int k0, short* tmp) {
        const short* wp = W + (size_t)gnW * K + k0 + c4 * 8;
        i32x2 a = *(const i32x2*)wp;
        i32x2 b = *(const i32x2*)(wp + 4);
        *(i32x2*)&tmp[0] = a; *(i32x2*)&tmp[4] = b;
    };

    ldA(0, av);
    ldW(0, wv);

    int ph = 0;
    for (int k0 = 0; k0 < K; k0 += 32, ph ^= 1) {
        *(i32x4*)&As[ph][row * 40 + c4 * 8] = *(i32x4*)av;
        *(i32x4*)&Bs[ph][row * 40 + c4 * 8] = *(i32x4*)wv;
        if (k0 + 32 < K) {
            ldA(k0 + 32, av);
            ldW(k0 + 32, wv);
        }
        __syncthreads();

        bf16x8 af[2], bf[2];
#pragma unroll
        for (int mi = 0; mi < 2; ++mi) af[mi] = *(const bf16x8*)&As[ph][(wm + mi * 16 + l15) * 40 + h * 8];
#pragma unroll
        for (int nj = 0; nj < 2; ++nj) bf[nj] = *(const bf16x8*)&Bs[ph][(wn + nj * 16 + l15) * 40 + h * 8];
#pragma unroll
        for (int mi = 0; mi < 2; ++mi)
#pragma unroll
            for (int nj = 0; nj < 2; ++nj) {
                if (TROUT)
                    acc[mi][nj] = __builtin_amdgcn_mfma_f32_16x16x32_bf16(bf[nj], af[mi], acc[mi][nj], 0, 0, 0);
                else
                    acc[mi][nj] = __builtin_amdgcn_mfma_f32_16x16x32_bf16(af[mi], bf[nj], acc[mi][nj], 0, 0, 0);
            }
    }

    if (!TROUT) {
#pragma unroll
        for (int mi = 0; mi < 2; ++mi) {
#pragma unroll
            for (int nj = 0; nj < 2; ++nj) {
                int gn = bn + wn + nj * 16 + l15;
#pragma unroll
                for (int r = 0; r < 4; ++r) {
                    int gm = bm + wm + mi * 16 + h * 4 + r;
                    size_t oi = (size_t)gm * N + gn;
                    if (ADD) outp[oi] += acc[mi][nj][r];
                    else     outp[oi] = acc[mi][nj][r];
                }
            }
        }
    } else {
#pragma unroll
        for (int mi = 0; mi < 2; ++mi) {
            int gm = bm + wm + mi * 16 + l15;
#pragma unroll
            for (int nj = 0; nj < 2; ++nj)
#pragma unroll
                for (int r = 0; r < 4; ++r) {
                    int gn = bn + wn + nj * 16 + h * 4 + r;
                    outp[(size_t)gn * M + gm] = acc[mi][nj][r];
                }
        }
    }
}

// ---------------------------------------------------------------------------
// S2T GEMM with fused im2col (r15 verbatim): 2-deep register prefetch.
// ---------------------------------------------------------------------------
__global__ __launch_bounds__(256) void mmim_k(const float* __restrict__ buf,
                                              const short* __restrict__ W,
                                              float* __restrict__ outp) {
    const int N = 128, K = 640;
    __shared__ __align__(16) short As[2][128 * 40];
    __shared__ __align__(16) short Bs[2][64 * 40];
    const int tid = threadIdx.x;
    const int bm = blockIdx.x * 128;
    const int bn = blockIdx.y * 64;
    const int w = tid >> 6, lane = tid & 63;
    const int h = lane >> 4, l15 = lane & 15;
    const int wm = (w >> 1) * 64, wn = (w & 1) * 32;

    const int rowA0 = tid >> 2, c4 = tid & 3;
    const int rowA1 = rowA0 + 64;
    const int gnW = bn + rowA0;

    f32x4 acc[4][2];
#pragma unroll
    for (int i = 0; i < 4; ++i)
#pragma unroll
        for (int j = 0; j < 2; ++j) acc[i][j] = (f32x4){0.f, 0.f, 0.f, 0.f};

    auto ldA = [&](int row, int k0, short* tmp) {
        int t = bm + row;
        int l = t & 1023, n = t >> 10;
        int y = l >> 5, x = l & 31;
        int k = k0 + c4 * 8;
        int tap = k >> 6, cc0 = k & 63;
        bool ok = (tap < 9);
        int ti = 0, tj = 0;
        if (ok) { ti = tap / 3; tj = tap - ti * 3; }
        int yy = y + ti - 1, xx = x + tj - 1;
        ok = ok && (yy >= 0) && (yy < 32) && (xx >= 0) && (xx < 32);
        if (ok) {
            const float* bp = buf + (size_t)cc0 * M_TOK + (n << 10) + (yy << 5) + xx;
#pragma unroll
            for (int i = 0; i < 8; ++i) tmp[i] = (short)f2b(bp[(size_t)i * M_TOK]);
        } else {
#pragma unroll
            for (int i = 0; i < 8; ++i) tmp[i] = 0;
        }
    };
    auto ldW = [&](int k0, short* tmp) {
        const short* wp = W + (size_t)gnW * K + k0 + c4 * 8;
        i32x2 a = *(const i32x2*)wp;
        i32x2 b = *(const i32x2*)(wp + 4);
        *(i32x2*)&tmp[0] = a; *(i32x2*)&tmp[4] = b;
    };
    auto compute = [&](int ph) {
        bf16x8 af[4], bf[2];
#pragma unroll
        for (int mi = 0; mi < 4; ++mi) af[mi] = *(const bf16x8*)&As[ph][(wm + mi * 16 + l15) * 40 + h * 8];
#pragma unroll
        for (int nj = 0; nj < 2; ++nj) bf[nj] = *(const bf16x8*)&Bs[ph][(wn + nj * 16 + l15) * 40 + h * 8];
#pragma unroll
        for (int mi = 0; mi < 4; ++mi)
#pragma unroll
            for (int nj = 0; nj < 2; ++nj)
                acc[mi][nj] = __builtin_amdgcn_mfma_f32_16x16x32_bf16(af[mi], bf[nj], acc[mi][nj], 0, 0, 0);
    };

    short a0A[8], a1A[8], wvA[8];
    short a0B[8], a1B[8], wvB[8];
    ldA(rowA0, 0, a0A);  ldA(rowA1, 0, a1A);  ldW(0, wvA);
    ldA(rowA0, 32, a0B); ldA(rowA1, 32, a1B); ldW(32, wvB);

    for (int k0 = 0; k0 < K; k0 += 64) {
        *(i32x4*)&As[0][rowA0 * 40 + c4 * 8] = *(i32x4*)a0A;
        *(i32x4*)&As[0][rowA1 * 40 + c4 * 8] = *(i32x4*)a1A;
        *(i32x4*)&Bs[0][rowA0 * 40 + c4 * 8] = *(i32x4*)wvA;
        if (k0 + 64 < K) { ldA(rowA0, k0 + 64, a0A); ldA(rowA1, k0 + 64, a1A); ldW(k0 + 64, wvA); }
        __syncthreads();
        compute(0);
        *(i32x4*)&As[1][rowA0 * 40 + c4 * 8] = *(i32x4*)a0B;
        *(i32x4*)&As[1][rowA1 * 40 + c4 * 8] = *(i32x4*)a1B;
        *(i32x4*)&Bs[1][rowA0 * 40 + c4 * 8] = *(i32x4*)wvB;
        if (k0 + 96 < K) { ldA(rowA0, k0 + 96, a0B); ldA(rowA1, k0 + 96, a1B); ldW(k0 + 96, wvB); }
        __syncthreads();
        compute(1);
    }

#pragma unroll
    for (int mi = 0; mi < 4; ++mi) {
#pragma unroll
        for (int nj = 0; nj < 2; ++nj) {
            int gn = bn + wn + nj * 16 + l15;
#pragma unroll
            for (int r = 0; r < 4; ++r) {
                int gm = bm + wm + mi * 16 + h * 4 + r;
                outp[(size_t)gm * N + gn] = acc[mi][nj][r];
            }
        }
    }
}

// ---------------------------------------------------------------------------
// bf16 MFMA GEMM WIDE (r15 verbatim): 128x128 tile + 2-deep prefetch.
// ---------------------------------------------------------------------------
__global__ __launch_bounds__(256) void mmw_k(const short* __restrict__ A,
                                             const short* __restrict__ W,
                                             short* __restrict__ outp,
                                             int M, int N, int K) {
    __shared__ __align__(16) short As[2][128 * 40];
    __shared__ __align__(16) short Bs[2][128 * 40];
    const int tid = threadIdx.x;
    const int bm = blockIdx.x * 128;
    const int bn = blockIdx.y * 128;
    const int w = tid >> 6, lane = tid & 63;
    const int h = lane >> 4, l15 = lane & 15;
    const int wm = (w >> 1) * 64, wn = (w & 1) * 64;

    const int row0 = tid >> 2, c4 = tid & 3;
    const int row1 = row0 + 64;

    f32x4 acc[4][4];
#pragma unroll
    for (int i = 0; i < 4; ++i)
#pragma unroll
        for (int j = 0; j < 4; ++j) acc[i][j] = (f32x4){0.f, 0.f, 0.f, 0.f};

    auto ldA = [&](int row, int k0, short* tmp) {
        const short* ap = A + (size_t)(bm + row) * K + k0 + c4 * 8;
        i32x2 x = *(const i32x2*)ap;
        i32x2 y = *(const i32x2*)(ap + 4);
        *(i32x2*)&tmp[0] = x; *(i32x2*)&tmp[4] = y;
    };
    auto ldW = [&](int row, int k0, short* tmp) {
        int gn = bn + row;
        if (gn < N) {
            const short* wp = W + (size_t)gn * K + k0 + c4 * 8;
            i32x2 x = *(const i32x2*)wp;
            i32x2 y = *(const i32x2*)(wp + 4);
            *(i32x2*)&tmp[0] = x; *(i32x2*)&tmp[4] = y;
        } else {
#pragma unroll
            for (int i = 0; i < 8; ++i) tmp[i] = 0;
        }
    };
    auto compute = [&](int ph) {
        bf16x8 af[4], bf[4];
#pragma unroll
        for (int mi = 0; mi < 4; ++mi) af[mi] = *(const bf16x8*)&As[ph][(wm + mi * 16 + l15) * 40 + h * 8];
#pragma unroll
        for (int nj = 0; nj < 4; ++nj) bf[nj] = *(const bf16x8*)&Bs[ph][(wn + nj * 16 + l15) * 40 + h * 8];
#pragma unroll
        for (int mi = 0; mi < 4; ++mi)
#pragma unroll
            for (int nj = 0; nj < 4; ++nj)
                acc[mi][nj] = __builtin_amdgcn_mfma_f32_16x16x32_bf16(af[mi], bf[nj], acc[mi][nj], 0, 0, 0);
    };

    short a0A[8], a1A[8], b0A[8], b1A[8];
    short a0B[8], a1B[8], b0B[8], b1B[8];
    ldA(row0, 0, a0A);  ldA(row1, 0, a1A);  ldW(row0, 0, b0A);  ldW(row1, 0, b1A);
    ldA(row0, 32, a0B); ldA(row1, 32, a1B); ldW(row0, 32, b0B); ldW(row1, 32, b1B);

    for (int k0 = 0; k0 < K; k0 += 64) {
        *(i32x4*)&As[0][row0 * 40 + c4 * 8] = *(i32x4*)a0A;
        *(i32x4*)&As[0][row1 * 40 + c4 * 8] = *(i32x4*)a1A;
        *(i32x4*)&Bs[0][row0 * 40 + c4 * 8] = *(i32x4*)b0A;
        *(i32x4*)&Bs[0][row1 * 40 + c4 * 8] = *(i32x4*)b1A;
        if (k0 + 64 < K) {
            ldA(row0, k0 + 64, a0A); ldA(row1, k0 + 64, a1A);
            ldW(row0, k0 + 64, b0A); ldW(row1, k0 + 64, b1A);
        }
        __syncthreads();
        compute(0);
        *(i32x4*)&As[1][row0 * 40 + c4 * 8] = *(i32x4*)a0B;
        *(i32x4*)&As[1][row1 * 40 + c4 * 8] = *(i32x4*)a1B;
        *(i32x4*)&Bs[1][row0 * 40 + c4 * 8] = *(i32x4*)b0B;
        *(i32x4*)&Bs[1][row1 * 40 + c4 * 8] = *(i32x4*)b1B;
        if (k0 + 96 < K) {
            ldA(row0, k0 + 96, a0B); ldA(row1, k0 + 96, a1B);
            ldW(row0, k0 + 96, b0B); ldW(row1, k0 + 96, b1B);
        }
        __syncthreads();
        compute(1);
    }

#pragma unroll
    for (int mi = 0; mi < 4; ++mi) {
#pragma unroll
        for (int nj = 0; nj < 4; ++nj) {
            int gn = bn + wn + nj * 16 + l15;
            if (gn < N) {
#pragma unroll
                for (int r = 0; r < 4; ++r) {
                    int gm = bm + wm + mi * 16 + h * 4 + r;
                    outp[(size_t)gm * N + gn] = (short)f2b(acc[mi][nj][r]);
                }
            }
        }
    }
}

// ---------------------------------------------------------------------------
// LayerNorm D=128, fp32 in -> bf16 out.
// ---------------------------------------------------------------------------
__global__ __launch_bounds__(256) void ln_k(const float* __restrict__ in,
                                            const float* __restrict__ w,
                                            const float* __restrict__ b,
                                            short* __restrict__ out) {
    int t = blockIdx.x * 4 + (threadIdx.x >> 6);
    int lane = threadIdx.x & 63;
    float2 v = *(const float2*)(in + (size_t)t * 128 + lane * 2);
    float s = v.x + v.y, sq = v.x * v.x + v.y * v.y;
#pragma unroll
    for (int off = 32; off > 0; off >>= 1) { s += __shfl_xor(s, off); sq += __shfl_xor(sq, off); }
    float mean = s * (1.f / 128.f);
    float var = sq * (1.f / 128.f) - mean * mean;
    float rstd = rsqrtf(var + 1e-5f);
    float2 wv = *(const float2*)(w + lane * 2);
    float2 bv = *(const float2*)(b + lane * 2);
    float ox = (v.x - mean) * rstd * wv.x + bv.x;
    float oy = (v.y - mean) * rstd * wv.y + bv.y;
    ((unsigned*)out)[(size_t)t * 64 + lane] = f2b(ox) | ((unsigned)f2b(oy) << 16);
}

// ---------------------------------------------------------------------------
// Fused qkv depthwise 3x3 + l2norm(q,k) + temperature*log2e folded into q.
// ---------------------------------------------------------------------------
__global__ __launch_bounds__(256) void dwl2n_k(const short* __restrict__ in,
                                               const float* __restrict__ wqT,
                                               const float* __restrict__ temp,
                                               short* __restrict__ out) {
    int idx = blockIdx.x * 256 + threadIdx.x;    // < M*48
    int q = idx % 48;
    int t = idx / 48;
    int c0 = q * 8;
    int l = t & 1023, n = t >> 10;
    int y = l >> 5, x = l & 31;
    int tb = n << 10;

    float acc[8];
#pragma unroll
    for (int k = 0; k < 8; ++k) acc[k] = 0.f;

#pragma unroll
    for (int i = 0; i < 3; ++i) {
        int yy = y + i - 1;
        if (yy < 0 || yy >= 32) continue;
#pragma unroll
        for (int j = 0; j < 3; ++j) {
            int xx = x + j - 1;
            if (xx < 0 || xx >= 32) continue;
            bf16x8 d = *(const bf16x8*)(in + (size_t)(tb + (yy << 5) + xx) * 384 + c0);
            float4 wa = *(const float4*)(wqT + (i * 3 + j) * 384 + c0);
            float4 wb = *(const float4*)(wqT + (i * 3 + j) * 384 + c0 + 4);
            acc[0] += b2f((unsigned short)d[0]) * wa.x;
            acc[1] += b2f((unsigned short)d[1]) * wa.y;
            acc[2] += b2f((unsigned short)d[2]) * wa.z;
            acc[3] += b2f((unsigned short)d[3]) * wa.w;
            acc[4] += b2f((unsigned short)d[4]) * wb.x;
            acc[5] += b2f((unsigned short)d[5]) * wb.y;
            acc[6] += b2f((unsigned short)d[6]) * wb.z;
            acc[7] += b2f((unsigned short)d[7]) * wb.w;
        }
    }
    float ss = 0.f;
#pragma unroll
    for (int k = 0; k < 8; ++k) ss += acc[k] * acc[k];
    ss += __shfl_xor(ss, 1);
    ss += __shfl_xor(ss, 2);
    float sc;
    if (c0 < 128)       sc = (1.f / fmaxf(sqrtf(ss), 1e-12f)) * temp[c0 >> 5] * 1.44269504089f;
    else if (c0 < 256)  sc = 1.f / fmaxf(sqrtf(ss), 1e-12f);
    else                sc = 1.f;
    unsigned o[4];
#pragma unroll
    for (int k = 0; k < 4; ++k)
        o[k] = f2b(acc[2 * k] * sc) | ((unsigned)f2b(acc[2 * k + 1] * sc) << 16);
    *(i32x4*)(out + (size_t)t * 384 + c0) = *(i32x4*)o;
}

// ---------------------------------------------------------------------------
// Fused GDFN depthwise: dual 3x3 dwconv + exact gelu gate. out [M][352].
// ---------------------------------------------------------------------------
__global__ __launch_bounds__(256) void gdfn2_k(const short* __restrict__ in,
                                               const float* __restrict__ wgT,
                                               short* __restrict__ out) {
    int idx = blockIdx.x * 256 + threadIdx.x;    // < M*44
    int q = idx % 44;
    int t = idx / 44;
    int c0 = q * 8;
    short* op = out + (size_t)t * 352 + c0;
    if (q == 43) {
        *(i32x4*)op = (i32x4){0, 0, 0, 0};
        return;
    }
    int l = t & 1023, n = t >> 10;
    int y = l >> 5, x = l & 31;
    int tb = n << 10;

    float a[8], g[8];
#pragma unroll
    for (int k = 0; k < 8; ++k) { a[k] = 0.f; g[k] = 0.f; }

#pragma unroll
    for (int i = 0; i < 3; ++i) {
        int yy = y + i - 1;
        if (yy < 0 || yy >= 32) continue;
#pragma unroll
        for (int j = 0; j < 3; ++j) {
            int xx = x + j - 1;
            if (xx < 0 || xx >= 32) continue;
            const short* p = in + (size_t)(tb + (yy << 5) + xx) * 680 + c0;
            bf16x8 d1 = *(const bf16x8*)p;
            i32x2 d2a = *(const i32x2*)(p + 340);
            i32x2 d2b = *(const i32x2*)(p + 344);
            short d2[8];
            *(i32x2*)&d2[0] = d2a; *(i32x2*)&d2[4] = d2b;
            const float* wp = wgT + (i * 3 + j) * 680 + c0;
            float4 w1a = *(const float4*)wp;
            float4 w1b = *(const float4*)(wp + 4);
            float w1[8] = {w1a.x, w1a.y, w1a.z, w1a.w, w1b.x, w1b.y, w1b.z, w1b.w};
            float w2[8];
#pragma unroll
            for (int k = 0; k < 8; ++k) w2[k] = wp[340 + k];
#pragma unroll
            for (int k = 0; k < 8; ++k) {
                a[k] += b2f((unsigned short)d1[k]) * w1[k];
                g[k] += b2f((unsigned short)d2[k]) * w2[k];
            }
        }
    }
    unsigned o[4];
#pragma unroll
    for (int k = 0; k < 4; ++k) {
        float r0 = 0.5f * a[2 * k] * (1.f + erff(a[2 * k] * 0.70710678118f)) * g[2 * k];
        float r1 = 0.5f * a[2 * k + 1] * (1.f + erff(a[2 * k + 1] * 0.70710678118f)) * g[2 * k + 1];
        o[k] = f2b(r0) | ((unsigned)f2b(r1) << 16);
    }
    if (q == 42) { o[2] = 0; o[3] = 0; }
    *(i32x4*)op = *(i32x4*)o;
}

// ---------------------------------------------------------------------------
// MFMA flash attention v8: SPLIT-K (2 halves x 512 keys, exact since
// fixed-bound softmax is linear), 3200 blocks, 2-deep prefetch, setprio
// around MFMA cluster. Writes unnormalized o (f32) + partial denominators.
// ---------------------------------------------------------------------------
__global__ __launch_bounds__(256) void attn_k(const short* __restrict__ qkv,
                                              float* __restrict__ AOf,
                                              float* __restrict__ PS) {
    __shared__ __align__(16) short Ks[2][64 * 40];
    __shared__ __align__(16) short Vp[2][2048];
    const int b = blockIdx.x;                    // 3200
    const int orig = (b & 7) * 400 + (b >> 3);   // XCD-contiguous remap (8x400)
    const int kh = orig & 1;
    const int rest = orig >> 1;                  // 1600 = nh*16 + qt
    const int qt = rest & 15, nh = rest >> 4;
    const int hd = nh & 3, n = nh >> 2;
    const int tid = threadIdx.x;
    const int w = tid >> 6, lane = tid & 63;
    const int h = lane >> 4, l15 = lane & 15;
    const size_t base = (size_t)n * 1024 * 384;
    const int qrow = qt * 64 + w * 16 + l15;

    bf16x8 qf = *(const bf16x8*)(qkv + base + (size_t)qrow * 384 + hd * 32 + h * 8);
    f32x4 o0 = {0.f,0.f,0.f,0.f}, o1 = {0.f,0.f,0.f,0.f};
    f32x4 osum = {0.f,0.f,0.f,0.f};
    union { unsigned u[4]; bf16x8 v; } ones;
#pragma unroll
    for (int r = 0; r < 4; ++r) ones.u[r] = 0x3F803F80u;

    const int skey = tid >> 2, sc4 = tid & 3;
    const int sg = skey >> 5, skey5 = skey & 31;
    const int sh = (skey5 >> 2) & 3;
    const int sj = (skey5 & 3) + ((skey5 >> 4) << 2);
    const int sgran0 = (sg * 4 + sh) * 32 + sc4 * 8;
    const short* kbase = qkv + base + (size_t)(kh * 512 + skey) * 384 + 128 + hd * 32 + sc4 * 8;

    auto scatterV = [&](int nb, i32x4 vreg) {
        short vs[8];
        *(i32x4*)vs = vreg;
#pragma unroll
        for (int i = 0; i < 8; ++i) {
            int gran = sgran0 + i;
            gran ^= (gran >> 3) & 7;
            Vp[nb][gran * 8 + sj] = vs[i];
        }
    };
    auto compute = [&](int nb) {
        const bf16x8 kf0 = *(const bf16x8*)&Ks[nb][l15 * 40 + h * 8];
        const bf16x8 kf1 = *(const bf16x8*)&Ks[nb][(16 + l15) * 40 + h * 8];
        const bf16x8 kf2 = *(const bf16x8*)&Ks[nb][(32 + l15) * 40 + h * 8];
        const bf16x8 kf3 = *(const bf16x8*)&Ks[nb][(48 + l15) * 40 + h * 8];
        int gr0 = h * 32 + l15;            gr0 ^= (gr0 >> 3) & 7;
        int gr1 = h * 32 + 16 + l15;       gr1 ^= (gr1 >> 3) & 7;
        int gr2 = (4 + h) * 32 + l15;      gr2 ^= (gr2 >> 3) & 7;
        int gr3 = (4 + h) * 32 + 16 + l15; gr3 ^= (gr3 >> 3) & 7;
        const bf16x8 va0 = *(const bf16x8*)&Vp[nb][gr0 * 8];
        const bf16x8 va1 = *(const bf16x8*)&Vp[nb][gr1 * 8];
        const bf16x8 vb0 = *(const bf16x8*)&Vp[nb][gr2 * 8];
        const bf16x8 vb1 = *(const bf16x8*)&Vp[nb][gr3 * 8];
        const f32x4 z = {0.f, 0.f, 0.f, 0.f};

        __builtin_amdgcn_s_setprio(1);
        f32x4 s0 = __builtin_amdgcn_mfma_f32_16x16x32_bf16(kf0, qf, z, 0, 0, 0);
        f32x4 s1 = __builtin_amdgcn_mfma_f32_16x16x32_bf16(kf1, qf, z, 0, 0, 0);
        f32x4 s2 = __builtin_amdgcn_mfma_f32_16x16x32_bf16(kf2, qf, z, 0, 0, 0);
        f32x4 s3 = __builtin_amdgcn_mfma_f32_16x16x32_bf16(kf3, qf, z, 0, 0, 0);
        __builtin_amdgcn_s_setprio(0);
        float p[16];
#pragma unroll
        for (int r = 0; r < 4; ++r) {
            p[r]      = exp2f(s0[r]);
            p[4 + r]  = exp2f(s1[r]);
            p[8 + r]  = exp2f(s2[r]);
            p[12 + r] = exp2f(s3[r]);
        }
        union { unsigned u[4]; bf16x8 v; } pf1, pf2;
#pragma unroll
        for (int r = 0; r < 4; ++r) {
            pf1.u[r] = cvtpk(p[2 * r], p[2 * r + 1]);
            pf2.u[r] = cvtpk(p[8 + 2 * r], p[8 + 2 * r + 1]);
        }
        __builtin_amdgcn_s_setprio(1);
        osum = __builtin_amdgcn_mfma_f32_16x16x32_bf16(ones.v, pf1.v, osum, 0, 0, 0);
        osum = __builtin_amdgcn_mfma_f32_16x16x32_bf16(ones.v, pf2.v, osum, 0, 0, 0);
        o0 = __builtin_amdgcn_mfma_f32_16x16x32_bf16(va0, pf1.v, o0, 0, 0, 0);
        o1 = __builtin_amdgcn_mfma_f32_16x16x32_bf16(va1, pf1.v, o1, 0, 0, 0);
        o0 = __builtin_amdgcn_mfma_f32_16x16x32_bf16(vb0, pf2.v, o0, 0, 0, 0);
        o1 = __builtin_amdgcn_mfma_f32_16x16x32_bf16(vb1, pf2.v, o1, 0, 0, 0);
        __builtin_amdgcn_s_setprio(0);
    };

    i32x4 kregA = *(const i32x4*)kbase;
    i32x4 vregA = *(const i32x4*)(kbase + 128);
    i32x4 kregB = *(const i32x4*)(kbase + (size_t)64 * 384);
    i32x4 vregB = *(const i32x4*)(kbase + (size_t)64 * 384 + 128);

    for (int t = 0; t < 8; t += 2) {
        *(i32x4*)&Ks[0][skey * 40 + sc4 * 8] = kregA;
        scatterV(0, vregA);
        if (t + 2 < 8) {
            const short* kp = kbase + (size_t)(t + 2) * 64 * 384;
            kregA = *(const i32x4*)kp;
            vregA = *(const i32x4*)(kp + 128);
        }
        __syncthreads();
        compute(0);
        *(i32x4*)&Ks[1][skey * 40 + sc4 * 8] = kregB;
        scatterV(1, vregB);
        if (t + 3 < 8) {
            const short* kp = kbase + (size_t)(t + 3) * 64 * 384;
            kregB = *(const i32x4*)kp;
            vregB = *(const i32x4*)(kp + 128);
        }
        __syncthreads();
        compute(1);
    }

    // unnormalized partial output (f32) + partial denominator
    size_t ob = ((size_t)n * 1024 + qrow) * 128 + hd * 32;
    float* dst = AOf + (size_t)kh * (M_TOK * 128) + ob;
    *(float4*)(dst + h * 4)      = (float4){o0[0], o0[1], o0[2], o0[3]};
    *(float4*)(dst + 16 + h * 4) = (float4){o1[0], o1[1], o1[2], o1[3]};
    if (h == 0)
        PS[(size_t)kh * (M_TOK * 4) + ((size_t)n * 1024 + qrow) * 4 + hd] = osum[0];
}

// ---------------------------------------------------------------------------
// Split-K combine: AObf = (AO0 + AO1) / (ps0 + ps1), bf16 out.
// ---------------------------------------------------------------------------
__global__ __launch_bounds__(256) void comb_k(const float* __restrict__ AOf,
                                              const float* __restrict__ PS,
                                              short* __restrict__ out) {
    int idx = blockIdx.x * 256 + threadIdx.x;    // < M*16
    int g = idx & 15;
    int t = idx >> 4;
    int c0 = g * 8;
    const float* p0 = AOf + (size_t)t * 128 + c0;
    const float* p1 = p0 + (size_t)M_TOK * 128;
    int hd = c0 >> 5;
    float inv = 1.f / (PS[(size_t)t * 4 + hd] + PS[(size_t)M_TOK * 4 + (size_t)t * 4 + hd]);
    float4 a0 = *(const float4*)p0, a1 = *(const float4*)(p0 + 4);
    float4 b0 = *(const float4*)p1, b1 = *(const float4*)(p1 + 4);
    unsigned o[4];
    o[0] = f2b((a0.x + b0.x) * inv) | ((unsigned)f2b((a0.y + b0.y) * inv) << 16);
    o[1] = f2b((a0.z + b0.z) * inv) | ((unsigned)f2b((a0.w + b0.w) * inv) << 16);
    o[2] = f2b((a1.x + b1.x) * inv) | ((unsigned)f2b((a1.y + b1.y) * inv) << 16);
    o[3] = f2b((a1.z + b1.z) * inv) | ((unsigned)f2b((a1.w + b1.w) * inv) << 16);
    *(i32x4*)(out + (size_t)t * 128 + c0) = *(i32x4*)o;
}

// ---------------------------------------------------------------------------
extern "C" void kernel_launch(void* const* d_in, const int* in_sizes, int n_in,
                              void* d_out, int out_size, void* d_ws, size_t ws_size,
                              hipStream_t stream) {
    const float* buffer      = (const float*)d_in[0];
    const float* mlp_w       = (const float*)d_in[1];
    const float* ln_attn_w   = (const float*)d_in[2];
    const float* ln_attn_b   = (const float*)d_in[3];
    const float* ln_ffn_w    = (const float*)d_in[4];
    const float* ln_ffn_b    = (const float*)d_in[5];
    const float* qkv_w       = (const float*)d_in[6];
    const float* qkv_dw_w    = (const float*)d_in[7];
    const float* temperature = (const float*)d_in[8];
    const float* proj_attn_w = (const float*)d_in[9];
    const float* ffn_in_w    = (const float*)d_in[10];
    const float* ffn_dw_w    = (const float*)d_in[11];
    const float* ffn_out_w   = (const float*)d_in[12];
    const float* proj3d_w    = (const float*)d_in[13];

    char* wsb = (char*)d_ws;
    short* Wbf     = (short*)wsb;                 // 287744 bf16 weights
    short* mlpW    = Wbf;                         // [128][640] tap-major
    short* qkvW    = Wbf + 81920;                 // [384][128]
    short* projW   = Wbf + 131072;                // [128][128]
    short* ffnInW  = Wbf + 147456;                // [680][128]
    short* ffnOutW = Wbf + 234496;                // [128][352] (padded)
    short* p3dW    = Wbf + 279552;                // [64][128]
    float* wqT     = (float*)(wsb + 575488);      // [9][384] f32
    float* wgT     = (float*)(wsb + 589312);      // [9][680] f32
    float* tok     = (float*)(wsb + 33381792);    // [M][128] f32
    short* LNbf    = (short*)(wsb + 46488992);    // [M][128] bf16
    short* QKVpre  = (short*)(wsb + 53042592);    // [M][384] bf16
    short* qkvb    = (short*)(wsb + 72703392);    // [M][384] bf16
    short* AObf    = (short*)(wsb + 92364192);    // [M][128] bf16
    short* F1      = (short*)(wsb + 98917792);    // [M][680] bf16
    short* G       = (short*)(wsb + 133733792);   // [M][352] bf16 (padded)
    // split-K attn partials live inside the (not-yet-used) F1 region:
    float* AOf     = (float*)(wsb + 98917792);    // [2][M][128] f32 (26.2 MB)
    float* PSb     = (float*)(wsb + 125132192);   // [2][M][4]   f32 (0.8 MB)

    dim3 blk(256);

    prep_k<<<1162, blk, 0, stream>>>(mlp_w, qkv_w, proj_attn_w, ffn_in_w, ffn_out_w, proj3d_w,
                                     qkv_dw_w, ffn_dw_w, Wbf, wqT, wgT);

    // S2T: tok = im2col(buffer) @ mlp_w^T — fused im2col, 2-deep prefetch
    mmim_k<<<dim3(200, 2), blk, 0, stream>>>(buffer, mlpW, tok);
    ln_k<<<6400, blk, 0, stream>>>(tok, ln_attn_w, ln_attn_b, LNbf);
    // qkv 1x1 (bf16 out) — WIDE tile, 2-deep prefetch
    mmw_k<<<dim3(200, 3), blk, 0, stream>>>(LNbf, qkvW, QKVpre, M_TOK, 384, 128);
    // fused dwconv + l2norm + temperature fold
    dwl2n_k<<<4800, blk, 0, stream>>>(QKVpre, wqT, temperature, qkvb);
    // attention v8: split-K halves + combine
    attn_k<<<3200, blk, 0, stream>>>(qkvb, AOf, PSb);
    comb_k<<<1600, blk, 0, stream>>>(AOf, PSb, AObf);
    // proj + residual — 64x64 tiles
    mm64_k<true, false, false><<<dim3(400, 2), blk, 0, stream>>>(AObf, projW, tok, M_TOK, 128, 128);
    ln_k<<<6400, blk, 0, stream>>>(tok, ln_ffn_w, ln_ffn_b, LNbf);
    // ffn_in 1x1 (bf16 out) — WIDE tile, 2-deep prefetch
    mmw_k<<<dim3(200, 6), blk, 0, stream>>>(LNbf, ffnInW, F1, M_TOK, 680, 128);
    // fused GDFN dwconv + gelu gate -> G [M][352] (padded)
    gdfn2_k<<<4400, blk, 0, stream>>>(F1, wgT, G);
    // ffn_out + residual, K=352 — 64x64 tiles
    mm64_k<true, false, false><<<dim3(400, 2), blk, 0, stream>>>(G, ffnOutW, tok, M_TOK, 128, 352);
    // Token2SAI (transposed product) — 64x64 tiles
    mm64_k<false, true, true><<<dim3(400, 1), blk, 0, stream>>>(tok, p3dW, (float*)d_out, M_TOK, 64, 128);
}

// Round 18
// 201.386 us; speedup vs baseline: 1.0277x; 1.0277x over previous
//
#include <hip/hip_runtime.h>
#include <math.h>

#define M_TOK 25600   // 25 images * 1024 tokens

typedef __attribute__((ext_vector_type(8))) short bf16x8;
typedef __attribute__((ext_vector_type(4))) float f32x4;
typedef __attribute__((ext_vector_type(4))) int   i32x4;
typedef __attribute__((ext_vector_type(2))) int   i32x2;

__device__ __forceinline__ unsigned short f2b(float x) {
    unsigned u = __builtin_bit_cast(unsigned, x);
    return (unsigned short)((u + 0x7fffu + ((u >> 16) & 1u)) >> 16);
}
__device__ __forceinline__ float b2f(unsigned short h) {
    unsigned u = ((unsigned)h) << 16;
    return __builtin_bit_cast(float, u);
}
__device__ __forceinline__ unsigned cvtpk(float lo, float hi) {
    unsigned r;
    asm("v_cvt_pk_bf16_f32 %0, %1, %2" : "=v"(r) : "v"(lo), "v"(hi));
    return r;
}

// ---------------------------------------------------------------------------
// Merged prep (r14 verbatim): weight fp32->bf16 + dw-weight transposes.
// ---------------------------------------------------------------------------
__global__ __launch_bounds__(256) void prep_k(const float* __restrict__ s0, const float* __restrict__ s1,
                                              const float* __restrict__ s2, const float* __restrict__ s3,
                                              const float* __restrict__ s4, const float* __restrict__ s5,
                                              const float* __restrict__ qw, const float* __restrict__ fw,
                                              short* __restrict__ dst,
                                              float* __restrict__ wqT, float* __restrict__ wgT) {
    int i = blockIdx.x * 256 + threadIdx.x;      // < 297320
    if (i >= 297320) return;
    if (i < 287744) {
        if (i < 81920) {
            int r = i % 640, d = i / 640;        // k = tap*64 + cc (tap-major)
            int tap = r >> 6, cc = r & 63;
            dst[i] = (tap < 9) ? (short)f2b(s0[(d * 64 + cc) * 9 + tap]) : (short)0;
            return;
        }
        if (i >= 234496 && i < 279552) {         // ffn_out padded [128][352]
            int l = i - 234496;
            int row = l / 352, col = l % 352;
            dst[i] = (col < 340) ? (short)f2b(s4[row * 340 + col]) : (short)0;
            return;
        }
        const float* s; int off;
        if      (i < 131072) { s = s1; off = i - 81920; }
        else if (i < 147456) { s = s2; off = i - 131072; }
        else if (i < 234496) { s = s3; off = i - 147456; }
        else                 { s = s5; off = i - 279552; }
        dst[i] = (short)f2b(s[off]);
        return;
    }
    int j = i - 287744;                          // < 9576
    if (j < 3456) {
        int tap = j / 384, c = j % 384;
        wqT[j] = qw[c * 9 + tap];
    } else {
        int k = j - 3456;
        int tap = k / 680, c = k % 680;
        wgT[k] = fw[c * 9 + tap];
    }
}

// ---------------------------------------------------------------------------
// bf16 MFMA GEMM, 64x64 tile (r16 verbatim, PROVEN).
// ---------------------------------------------------------------------------
template <bool ADD, bool TROUT, bool AF32>
__global__ __launch_bounds__(256) void mm64_k(const void* __restrict__ Avp,
                                              const short* __restrict__ W,
                                              float* __restrict__ outp,
                                              int M, int N, int K) {
    __shared__ __align__(16) short As[2][64 * 40];
    __shared__ __align__(16) short Bs[2][64 * 40];
    const int tid = threadIdx.x;
    const int bm = blockIdx.x * 64;
    const int bn = blockIdx.y * 64;
    const int w = tid >> 6, lane = tid & 63;
    const int h = lane >> 4, l15 = lane & 15;
    const int wm = (w >> 1) * 32, wn = (w & 1) * 32;

    const int row = tid >> 2, c4 = tid & 3;
    const int gnW = bn + row;

    f32x4 acc[2][2];
#pragma unroll
    for (int i = 0; i < 2; ++i)
#pragma unroll
        for (int j = 0; j < 2; ++j) acc[i][j] = (f32x4){0.f, 0.f, 0.f, 0.f};

    short av[8], wv[8];

    auto ldA = [&](int k0, short* tmp) {
        int gk = k0 + c4 * 8;
        size_t abase = (size_t)(bm + row) * K + gk;
        if (AF32) {
            const float* ap = (const float*)Avp + abase;
            float4 va = *(const float4*)ap;
            float4 vb = *(const float4*)(ap + 4);
            tmp[0] = (short)f2b(va.x); tmp[1] = (short)f2b(va.y);
            tmp[2] = (short)f2b(va.z); tmp[3] = (short)f2b(va.w);
            tmp[4] = (short)f2b(vb.x); tmp[5] = (short)f2b(vb.y);
            tmp[6] = (short)f2b(vb.z); tmp[7] = (short)f2b(vb.w);
        } else {
            const short* ap = (const short*)Avp + abase;
            i32x2 a = *(const i32x2*)ap;
            i32x2 b = *(const i32x2*)(ap + 4);
            *(i32x2*)&tmp[0] = a; *(i32x2*)&tmp[4] = b;
        }
    };
    auto ldW = [&](int k0, short* tmp) {
        const short* wp = W + (size_t)gnW * K + k0 + c4 * 8;
        i32x2 a = *(const i32x2*)wp;
        i32x2 b = *(const i32x2*)(wp + 4);
        *(i32x2*)&tmp[0] = a; *(i32x2*)&tmp[4] = b;
    };

    ldA(0, av);
    ldW(0, wv);

    int ph = 0;
    for (int k0 = 0; k0 < K; k0 += 32, ph ^= 1) {
        *(i32x4*)&As[ph][row * 40 + c4 * 8] = *(i32x4*)av;
        *(i32x4*)&Bs[ph][row * 40 + c4 * 8] = *(i32x4*)wv;
        if (k0 + 32 < K) {
            ldA(k0 + 32, av);
            ldW(k0 + 32, wv);
        }
        __syncthreads();

        bf16x8 af[2], bf[2];
#pragma unroll
        for (int mi = 0; mi < 2; ++mi) af[mi] = *(const bf16x8*)&As[ph][(wm + mi * 16 + l15) * 40 + h * 8];
#pragma unroll
        for (int nj = 0; nj < 2; ++nj) bf[nj] = *(const bf16x8*)&Bs[ph][(wn + nj * 16 + l15) * 40 + h * 8];
#pragma unroll
        for (int mi = 0; mi < 2; ++mi)
#pragma unroll
            for (int nj = 0; nj < 2; ++nj) {
                if (TROUT)
                    acc[mi][nj] = __builtin_amdgcn_mfma_f32_16x16x32_bf16(bf[nj], af[mi], acc[mi][nj], 0, 0, 0);
                else
                    acc[mi][nj] = __builtin_amdgcn_mfma_f32_16x16x32_bf16(af[mi], bf[nj], acc[mi][nj], 0, 0, 0);
            }
    }

    if (!TROUT) {
#pragma unroll
        for (int mi = 0; mi < 2; ++mi) {
#pragma unroll
            for (int nj = 0; nj < 2; ++nj) {
                int gn = bn + wn + nj * 16 + l15;
#pragma unroll
                for (int r = 0; r < 4; ++r) {
                    int gm = bm + wm + mi * 16 + h * 4 + r;
                    size_t oi = (size_t)gm * N + gn;
                    if (ADD) outp[oi] += acc[mi][nj][r];
                    else     outp[oi] = acc[mi][nj][r];
                }
            }
        }
    } else {
#pragma unroll
        for (int mi = 0; mi < 2; ++mi) {
            int gm = bm + wm + mi * 16 + l15;
#pragma unroll
            for (int nj = 0; nj < 2; ++nj)
#pragma unroll
                for (int r = 0; r < 4; ++r) {
                    int gn = bn + wn + nj * 16 + h * 4 + r;
                    outp[(size_t)gn * M + gm] = acc[mi][nj][r];
                }
        }
    }
}

// ---------------------------------------------------------------------------
// S2T GEMM with fused im2col (r15 verbatim): 2-deep register prefetch.
// ---------------------------------------------------------------------------
__global__ __launch_bounds__(256) void mmim_k(const float* __restrict__ buf,
                                              const short* __restrict__ W,
                                              float* __restrict__ outp) {
    const int N = 128, K = 640;
    __shared__ __align__(16) short As[2][128 * 40];
    __shared__ __align__(16) short Bs[2][64 * 40];
    const int tid = threadIdx.x;
    const int bm = blockIdx.x * 128;
    const int bn = blockIdx.y * 64;
    const int w = tid >> 6, lane = tid & 63;
    const int h = lane >> 4, l15 = lane & 15;
    const int wm = (w >> 1) * 64, wn = (w & 1) * 32;

    const int rowA0 = tid >> 2, c4 = tid & 3;
    const int rowA1 = rowA0 + 64;
    const int gnW = bn + rowA0;

    f32x4 acc[4][2];
#pragma unroll
    for (int i = 0; i < 4; ++i)
#pragma unroll
        for (int j = 0; j < 2; ++j) acc[i][j] = (f32x4){0.f, 0.f, 0.f, 0.f};

    auto ldA = [&](int row, int k0, short* tmp) {
        int t = bm + row;
        int l = t & 1023, n = t >> 10;
        int y = l >> 5, x = l & 31;
        int k = k0 + c4 * 8;
        int tap = k >> 6, cc0 = k & 63;
        bool ok = (tap < 9);
        int ti = 0, tj = 0;
        if (ok) { ti = tap / 3; tj = tap - ti * 3; }
        int yy = y + ti - 1, xx = x + tj - 1;
        ok = ok && (yy >= 0) && (yy < 32) && (xx >= 0) && (xx < 32);
        if (ok) {
            const float* bp = buf + (size_t)cc0 * M_TOK + (n << 10) + (yy << 5) + xx;
#pragma unroll
            for (int i = 0; i < 8; ++i) tmp[i] = (short)f2b(bp[(size_t)i * M_TOK]);
        } else {
#pragma unroll
            for (int i = 0; i < 8; ++i) tmp[i] = 0;
        }
    };
    auto ldW = [&](int k0, short* tmp) {
        const short* wp = W + (size_t)gnW * K + k0 + c4 * 8;
        i32x2 a = *(const i32x2*)wp;
        i32x2 b = *(const i32x2*)(wp + 4);
        *(i32x2*)&tmp[0] = a; *(i32x2*)&tmp[4] = b;
    };
    auto compute = [&](int ph) {
        bf16x8 af[4], bf[2];
#pragma unroll
        for (int mi = 0; mi < 4; ++mi) af[mi] = *(const bf16x8*)&As[ph][(wm + mi * 16 + l15) * 40 + h * 8];
#pragma unroll
        for (int nj = 0; nj < 2; ++nj) bf[nj] = *(const bf16x8*)&Bs[ph][(wn + nj * 16 + l15) * 40 + h * 8];
#pragma unroll
        for (int mi = 0; mi < 4; ++mi)
#pragma unroll
            for (int nj = 0; nj < 2; ++nj)
                acc[mi][nj] = __builtin_amdgcn_mfma_f32_16x16x32_bf16(af[mi], bf[nj], acc[mi][nj], 0, 0, 0);
    };

    short a0A[8], a1A[8], wvA[8];
    short a0B[8], a1B[8], wvB[8];
    ldA(rowA0, 0, a0A);  ldA(rowA1, 0, a1A);  ldW(0, wvA);
    ldA(rowA0, 32, a0B); ldA(rowA1, 32, a1B); ldW(32, wvB);

    for (int k0 = 0; k0 < K; k0 += 64) {
        *(i32x4*)&As[0][rowA0 * 40 + c4 * 8] = *(i32x4*)a0A;
        *(i32x4*)&As[0][rowA1 * 40 + c4 * 8] = *(i32x4*)a1A;
        *(i32x4*)&Bs[0][rowA0 * 40 + c4 * 8] = *(i32x4*)wvA;
        if (k0 + 64 < K) { ldA(rowA0, k0 + 64, a0A); ldA(rowA1, k0 + 64, a1A); ldW(k0 + 64, wvA); }
        __syncthreads();
        compute(0);
        *(i32x4*)&As[1][rowA0 * 40 + c4 * 8] = *(i32x4*)a0B;
        *(i32x4*)&As[1][rowA1 * 40 + c4 * 8] = *(i32x4*)a1B;
        *(i32x4*)&Bs[1][rowA0 * 40 + c4 * 8] = *(i32x4*)wvB;
        if (k0 + 96 < K) { ldA(rowA0, k0 + 96, a0B); ldA(rowA1, k0 + 96, a1B); ldW(k0 + 96, wvB); }
        __syncthreads();
        compute(1);
    }

#pragma unroll
    for (int mi = 0; mi < 4; ++mi) {
#pragma unroll
        for (int nj = 0; nj < 2; ++nj) {
            int gn = bn + wn + nj * 16 + l15;
#pragma unroll
            for (int r = 0; r < 4; ++r) {
                int gm = bm + wm + mi * 16 + h * 4 + r;
                outp[(size_t)gm * N + gn] = acc[mi][nj][r];
            }
        }
    }
}

// ---------------------------------------------------------------------------
// bf16 MFMA GEMM WIDE (r15 verbatim): 128x128 tile + 2-deep prefetch.
// ---------------------------------------------------------------------------
__global__ __launch_bounds__(256) void mmw_k(const short* __restrict__ A,
                                             const short* __restrict__ W,
                                             short* __restrict__ outp,
                                             int M, int N, int K) {
    __shared__ __align__(16) short As[2][128 * 40];
    __shared__ __align__(16) short Bs[2][128 * 40];
    const int tid = threadIdx.x;
    const int bm = blockIdx.x * 128;
    const int bn = blockIdx.y * 128;
    const int w = tid >> 6, lane = tid & 63;
    const int h = lane >> 4, l15 = lane & 15;
    const int wm = (w >> 1) * 64, wn = (w & 1) * 64;

    const int row0 = tid >> 2, c4 = tid & 3;
    const int row1 = row0 + 64;

    f32x4 acc[4][4];
#pragma unroll
    for (int i = 0; i < 4; ++i)
#pragma unroll
        for (int j = 0; j < 4; ++j) acc[i][j] = (f32x4){0.f, 0.f, 0.f, 0.f};

    auto ldA = [&](int row, int k0, short* tmp) {
        const short* ap = A + (size_t)(bm + row) * K + k0 + c4 * 8;
        i32x2 x = *(const i32x2*)ap;
        i32x2 y = *(const i32x2*)(ap + 4);
        *(i32x2*)&tmp[0] = x; *(i32x2*)&tmp[4] = y;
    };
    auto ldW = [&](int row, int k0, short* tmp) {
        int gn = bn + row;
        if (gn < N) {
            const short* wp = W + (size_t)gn * K + k0 + c4 * 8;
            i32x2 x = *(const i32x2*)wp;
            i32x2 y = *(const i32x2*)(wp + 4);
            *(i32x2*)&tmp[0] = x; *(i32x2*)&tmp[4] = y;
        } else {
#pragma unroll
            for (int i = 0; i < 8; ++i) tmp[i] = 0;
        }
    };
    auto compute = [&](int ph) {
        bf16x8 af[4], bf[4];
#pragma unroll
        for (int mi = 0; mi < 4; ++mi) af[mi] = *(const bf16x8*)&As[ph][(wm + mi * 16 + l15) * 40 + h * 8];
#pragma unroll
        for (int nj = 0; nj < 4; ++nj) bf[nj] = *(const bf16x8*)&Bs[ph][(wn + nj * 16 + l15) * 40 + h * 8];
#pragma unroll
        for (int mi = 0; mi < 4; ++mi)
#pragma unroll
            for (int nj = 0; nj < 4; ++nj)
                acc[mi][nj] = __builtin_amdgcn_mfma_f32_16x16x32_bf16(af[mi], bf[nj], acc[mi][nj], 0, 0, 0);
    };

    short a0A[8], a1A[8], b0A[8], b1A[8];
    short a0B[8], a1B[8], b0B[8], b1B[8];
    ldA(row0, 0, a0A);  ldA(row1, 0, a1A);  ldW(row0, 0, b0A);  ldW(row1, 0, b1A);
    ldA(row0, 32, a0B); ldA(row1, 32, a1B); ldW(row0, 32, b0B); ldW(row1, 32, b1B);

    for (int k0 = 0; k0 < K; k0 += 64) {
        *(i32x4*)&As[0][row0 * 40 + c4 * 8] = *(i32x4*)a0A;
        *(i32x4*)&As[0][row1 * 40 + c4 * 8] = *(i32x4*)a1A;
        *(i32x4*)&Bs[0][row0 * 40 + c4 * 8] = *(i32x4*)b0A;
        *(i32x4*)&Bs[0][row1 * 40 + c4 * 8] = *(i32x4*)b1A;
        if (k0 + 64 < K) {
            ldA(row0, k0 + 64, a0A); ldA(row1, k0 + 64, a1A);
            ldW(row0, k0 + 64, b0A); ldW(row1, k0 + 64, b1A);
        }
        __syncthreads();
        compute(0);
        *(i32x4*)&As[1][row0 * 40 + c4 * 8] = *(i32x4*)a0B;
        *(i32x4*)&As[1][row1 * 40 + c4 * 8] = *(i32x4*)a1B;
        *(i32x4*)&Bs[1][row0 * 40 + c4 * 8] = *(i32x4*)b0B;
        *(i32x4*)&Bs[1][row1 * 40 + c4 * 8] = *(i32x4*)b1B;
        if (k0 + 96 < K) {
            ldA(row0, k0 + 96, a0B); ldA(row1, k0 + 96, a1B);
            ldW(row0, k0 + 96, b0B); ldW(row1, k0 + 96, b1B);
        }
        __syncthreads();
        compute(1);
    }

#pragma unroll
    for (int mi = 0; mi < 4; ++mi) {
#pragma unroll
        for (int nj = 0; nj < 4; ++nj) {
            int gn = bn + wn + nj * 16 + l15;
            if (gn < N) {
#pragma unroll
                for (int r = 0; r < 4; ++r) {
                    int gm = bm + wm + mi * 16 + h * 4 + r;
                    outp[(size_t)gm * N + gn] = (short)f2b(acc[mi][nj][r]);
                }
            }
        }
    }
}

// ---------------------------------------------------------------------------
// LayerNorm D=128, fp32 in -> bf16 out.
// ---------------------------------------------------------------------------
__global__ __launch_bounds__(256) void ln_k(const float* __restrict__ in,
                                            const float* __restrict__ w,
                                            const float* __restrict__ b,
                                            short* __restrict__ out) {
    int t = blockIdx.x * 4 + (threadIdx.x >> 6);
    int lane = threadIdx.x & 63;
    float2 v = *(const float2*)(in + (size_t)t * 128 + lane * 2);
    float s = v.x + v.y, sq = v.x * v.x + v.y * v.y;
#pragma unroll
    for (int off = 32; off > 0; off >>= 1) { s += __shfl_xor(s, off); sq += __shfl_xor(sq, off); }
    float mean = s * (1.f / 128.f);
    float var = sq * (1.f / 128.f) - mean * mean;
    float rstd = rsqrtf(var + 1e-5f);
    float2 wv = *(const float2*)(w + lane * 2);
    float2 bv = *(const float2*)(b + lane * 2);
    float ox = (v.x - mean) * rstd * wv.x + bv.x;
    float oy = (v.y - mean) * rstd * wv.y + bv.y;
    ((unsigned*)out)[(size_t)t * 64 + lane] = f2b(ox) | ((unsigned)f2b(oy) << 16);
}

// ---------------------------------------------------------------------------
// Fused qkv depthwise 3x3 + l2norm(q,k) + temperature*log2e folded into q.
// ---------------------------------------------------------------------------
__global__ __launch_bounds__(256) void dwl2n_k(const short* __restrict__ in,
                                               const float* __restrict__ wqT,
                                               const float* __restrict__ temp,
                                               short* __restrict__ out) {
    int idx = blockIdx.x * 256 + threadIdx.x;    // < M*48
    int q = idx % 48;
    int t = idx / 48;
    int c0 = q * 8;
    int l = t & 1023, n = t >> 10;
    int y = l >> 5, x = l & 31;
    int tb = n << 10;

    float acc[8];
#pragma unroll
    for (int k = 0; k < 8; ++k) acc[k] = 0.f;

#pragma unroll
    for (int i = 0; i < 3; ++i) {
        int yy = y + i - 1;
        if (yy < 0 || yy >= 32) continue;
#pragma unroll
        for (int j = 0; j < 3; ++j) {
            int xx = x + j - 1;
            if (xx < 0 || xx >= 32) continue;
            bf16x8 d = *(const bf16x8*)(in + (size_t)(tb + (yy << 5) + xx) * 384 + c0);
            float4 wa = *(const float4*)(wqT + (i * 3 + j) * 384 + c0);
            float4 wb = *(const float4*)(wqT + (i * 3 + j) * 384 + c0 + 4);
            acc[0] += b2f((unsigned short)d[0]) * wa.x;
            acc[1] += b2f((unsigned short)d[1]) * wa.y;
            acc[2] += b2f((unsigned short)d[2]) * wa.z;
            acc[3] += b2f((unsigned short)d[3]) * wa.w;
            acc[4] += b2f((unsigned short)d[4]) * wb.x;
            acc[5] += b2f((unsigned short)d[5]) * wb.y;
            acc[6] += b2f((unsigned short)d[6]) * wb.z;
            acc[7] += b2f((unsigned short)d[7]) * wb.w;
        }
    }
    float ss = 0.f;
#pragma unroll
    for (int k = 0; k < 8; ++k) ss += acc[k] * acc[k];
    ss += __shfl_xor(ss, 1);
    ss += __shfl_xor(ss, 2);
    float sc;
    if (c0 < 128)       sc = (1.f / fmaxf(sqrtf(ss), 1e-12f)) * temp[c0 >> 5] * 1.44269504089f;
    else if (c0 < 256)  sc = 1.f / fmaxf(sqrtf(ss), 1e-12f);
    else                sc = 1.f;
    unsigned o[4];
#pragma unroll
    for (int k = 0; k < 4; ++k)
        o[k] = f2b(acc[2 * k] * sc) | ((unsigned)f2b(acc[2 * k + 1] * sc) << 16);
    *(i32x4*)(out + (size_t)t * 384 + c0) = *(i32x4*)o;
}

// ---------------------------------------------------------------------------
// Fused GDFN depthwise: dual 3x3 dwconv + exact gelu gate. out [M][352].
// ---------------------------------------------------------------------------
__global__ __launch_bounds__(256) void gdfn2_k(const short* __restrict__ in,
                                               const float* __restrict__ wgT,
                                               short* __restrict__ out) {
    int idx = blockIdx.x * 256 + threadIdx.x;    // < M*44
    int q = idx % 44;
    int t = idx / 44;
    int c0 = q * 8;
    short* op = out + (size_t)t * 352 + c0;
    if (q == 43) {
        *(i32x4*)op = (i32x4){0, 0, 0, 0};
        return;
    }
    int l = t & 1023, n = t >> 10;
    int y = l >> 5, x = l & 31;
    int tb = n << 10;

    float a[8], g[8];
#pragma unroll
    for (int k = 0; k < 8; ++k) { a[k] = 0.f; g[k] = 0.f; }

#pragma unroll
    for (int i = 0; i < 3; ++i) {
        int yy = y + i - 1;
        if (yy < 0 || yy >= 32) continue;
#pragma unroll
        for (int j = 0; j < 3; ++j) {
            int xx = x + j - 1;
            if (xx < 0 || xx >= 32) continue;
            const short* p = in + (size_t)(tb + (yy << 5) + xx) * 680 + c0;
            bf16x8 d1 = *(const bf16x8*)p;
            i32x2 d2a = *(const i32x2*)(p + 340);
            i32x2 d2b = *(const i32x2*)(p + 344);
            short d2[8];
            *(i32x2*)&d2[0] = d2a; *(i32x2*)&d2[4] = d2b;
            const float* wp = wgT + (i * 3 + j) * 680 + c0;
            float4 w1a = *(const float4*)wp;
            float4 w1b = *(const float4*)(wp + 4);
            float w1[8] = {w1a.x, w1a.y, w1a.z, w1a.w, w1b.x, w1b.y, w1b.z, w1b.w};
            float w2[8];
#pragma unroll
            for (int k = 0; k < 8; ++k) w2[k] = wp[340 + k];
#pragma unroll
            for (int k = 0; k < 8; ++k) {
                a[k] += b2f((unsigned short)d1[k]) * w1[k];
                g[k] += b2f((unsigned short)d2[k]) * w2[k];
            }
        }
    }
    unsigned o[4];
#pragma unroll
    for (int k = 0; k < 4; ++k) {
        float r0 = 0.5f * a[2 * k] * (1.f + erff(a[2 * k] * 0.70710678118f)) * g[2 * k];
        float r1 = 0.5f * a[2 * k + 1] * (1.f + erff(a[2 * k + 1] * 0.70710678118f)) * g[2 * k + 1];
        o[k] = f2b(r0) | ((unsigned)f2b(r1) << 16);
    }
    if (q == 42) { o[2] = 0; o[3] = 0; }
    *(i32x4*)op = *(i32x4*)o;
}

// ---------------------------------------------------------------------------
// MFMA flash attention v9 = r16's v7 (PROVEN 43.4us) + s_setprio around the
// MFMA clusters (isolated A/B of the m191 technique).
// ---------------------------------------------------------------------------
__global__ __launch_bounds__(256) void attn_k(const short* __restrict__ qkv,
                                              short* __restrict__ outp) {
    __shared__ __align__(16) short Ks[2][64 * 40];
    __shared__ __align__(16) short Vp[2][2048];
    const int b = blockIdx.x;
    const int orig = (b & 7) * 200 + (b >> 3);   // XCD-contiguous remap
    const int qt = orig & 15, nh = orig >> 4;
    const int hd = nh & 3, n = nh >> 2;
    const int tid = threadIdx.x;
    const int w = tid >> 6, lane = tid & 63;
    const int h = lane >> 4, l15 = lane & 15;
    const size_t base = (size_t)n * 1024 * 384;
    const int qrow = qt * 64 + w * 16 + l15;

    bf16x8 qf = *(const bf16x8*)(qkv + base + (size_t)qrow * 384 + hd * 32 + h * 8);
    f32x4 o0 = {0.f,0.f,0.f,0.f}, o1 = {0.f,0.f,0.f,0.f};
    f32x4 osum = {0.f,0.f,0.f,0.f};
    union { unsigned u[4]; bf16x8 v; } ones;
#pragma unroll
    for (int r = 0; r < 4; ++r) ones.u[r] = 0x3F803F80u;

    const int skey = tid >> 2, sc4 = tid & 3;
    const int sg = skey >> 5, skey5 = skey & 31;
    const int sh = (skey5 >> 2) & 3;
    const int sj = (skey5 & 3) + ((skey5 >> 4) << 2);
    const int sgran0 = (sg * 4 + sh) * 32 + sc4 * 8;
    const short* kbase = qkv + base + (size_t)skey * 384 + 128 + hd * 32 + sc4 * 8;

    auto scatterV = [&](int nb, i32x4 vreg) {
        short vs[8];
        *(i32x4*)vs = vreg;
#pragma unroll
        for (int i = 0; i < 8; ++i) {
            int gran = sgran0 + i;
            gran ^= (gran >> 3) & 7;
            Vp[nb][gran * 8 + sj] = vs[i];
        }
    };
    auto compute = [&](int nb) {
        const bf16x8 kf0 = *(const bf16x8*)&Ks[nb][l15 * 40 + h * 8];
        const bf16x8 kf1 = *(const bf16x8*)&Ks[nb][(16 + l15) * 40 + h * 8];
        const bf16x8 kf2 = *(const bf16x8*)&Ks[nb][(32 + l15) * 40 + h * 8];
        const bf16x8 kf3 = *(const bf16x8*)&Ks[nb][(48 + l15) * 40 + h * 8];
        int gr0 = h * 32 + l15;            gr0 ^= (gr0 >> 3) & 7;
        int gr1 = h * 32 + 16 + l15;       gr1 ^= (gr1 >> 3) & 7;
        int gr2 = (4 + h) * 32 + l15;      gr2 ^= (gr2 >> 3) & 7;
        int gr3 = (4 + h) * 32 + 16 + l15; gr3 ^= (gr3 >> 3) & 7;
        const bf16x8 va0 = *(const bf16x8*)&Vp[nb][gr0 * 8];
        const bf16x8 va1 = *(const bf16x8*)&Vp[nb][gr1 * 8];
        const bf16x8 vb0 = *(const bf16x8*)&Vp[nb][gr2 * 8];
        const bf16x8 vb1 = *(const bf16x8*)&Vp[nb][gr3 * 8];
        const f32x4 z = {0.f, 0.f, 0.f, 0.f};

        __builtin_amdgcn_s_setprio(1);
        f32x4 s0 = __builtin_amdgcn_mfma_f32_16x16x32_bf16(kf0, qf, z, 0, 0, 0);
        f32x4 s1 = __builtin_amdgcn_mfma_f32_16x16x32_bf16(kf1, qf, z, 0, 0, 0);
        f32x4 s2 = __builtin_amdgcn_mfma_f32_16x16x32_bf16(kf2, qf, z, 0, 0, 0);
        f32x4 s3 = __builtin_amdgcn_mfma_f32_16x16x32_bf16(kf3, qf, z, 0, 0, 0);
        __builtin_amdgcn_s_setprio(0);
        float p[16];
#pragma unroll
        for (int r = 0; r < 4; ++r) {
            p[r]      = exp2f(s0[r]);
            p[4 + r]  = exp2f(s1[r]);
            p[8 + r]  = exp2f(s2[r]);
            p[12 + r] = exp2f(s3[r]);
        }
        union { unsigned u[4]; bf16x8 v; } pf1, pf2;
#pragma unroll
        for (int r = 0; r < 4; ++r) {
            pf1.u[r] = cvtpk(p[2 * r], p[2 * r + 1]);
            pf2.u[r] = cvtpk(p[8 + 2 * r], p[8 + 2 * r + 1]);
        }
        __builtin_amdgcn_s_setprio(1);
        osum = __builtin_amdgcn_mfma_f32_16x16x32_bf16(ones.v, pf1.v, osum, 0, 0, 0);
        osum = __builtin_amdgcn_mfma_f32_16x16x32_bf16(ones.v, pf2.v, osum, 0, 0, 0);
        o0 = __builtin_amdgcn_mfma_f32_16x16x32_bf16(va0, pf1.v, o0, 0, 0, 0);
        o1 = __builtin_amdgcn_mfma_f32_16x16x32_bf16(va1, pf1.v, o1, 0, 0, 0);
        o0 = __builtin_amdgcn_mfma_f32_16x16x32_bf16(vb0, pf2.v, o0, 0, 0, 0);
        o1 = __builtin_amdgcn_mfma_f32_16x16x32_bf16(vb1, pf2.v, o1, 0, 0, 0);
        __builtin_amdgcn_s_setprio(0);
    };

    i32x4 kregA = *(const i32x4*)kbase;
    i32x4 vregA = *(const i32x4*)(kbase + 128);
    i32x4 kregB = *(const i32x4*)(kbase + (size_t)64 * 384);
    i32x4 vregB = *(const i32x4*)(kbase + (size_t)64 * 384 + 128);

    for (int t = 0; t < 16; t += 2) {
        *(i32x4*)&Ks[0][skey * 40 + sc4 * 8] = kregA;
        scatterV(0, vregA);
        if (t + 2 < 16) {
            const short* kp = kbase + (size_t)(t + 2) * 64 * 384;
            kregA = *(const i32x4*)kp;
            vregA = *(const i32x4*)(kp + 128);
        }
        __syncthreads();
        compute(0);
        *(i32x4*)&Ks[1][skey * 40 + sc4 * 8] = kregB;
        scatterV(1, vregB);
        if (t + 3 < 16) {
            const short* kp = kbase + (size_t)(t + 3) * 64 * 384;
            kregB = *(const i32x4*)kp;
            vregB = *(const i32x4*)(kp + 128);
        }
        __syncthreads();
        compute(1);
    }

    float inv = 1.f / osum[0];

    size_t ob = ((size_t)n * 1024 + qrow) * 128 + hd * 32;
    unsigned u;
    u = f2b(o0[0] * inv) | ((unsigned)f2b(o0[1] * inv) << 16); *(unsigned*)(outp + ob + h * 4) = u;
    u = f2b(o0[2] * inv) | ((unsigned)f2b(o0[3] * inv) << 16); *(unsigned*)(outp + ob + h * 4 + 2) = u;
    u = f2b(o1[0] * inv) | ((unsigned)f2b(o1[1] * inv) << 16); *(unsigned*)(outp + ob + 16 + h * 4) = u;
    u = f2b(o1[2] * inv) | ((unsigned)f2b(o1[3] * inv) << 16); *(unsigned*)(outp + ob + 16 + h * 4 + 2) = u;
}

// ---------------------------------------------------------------------------
extern "C" void kernel_launch(void* const* d_in, const int* in_sizes, int n_in,
                              void* d_out, int out_size, void* d_ws, size_t ws_size,
                              hipStream_t stream) {
    const float* buffer      = (const float*)d_in[0];
    const float* mlp_w       = (const float*)d_in[1];
    const float* ln_attn_w   = (const float*)d_in[2];
    const float* ln_attn_b   = (const float*)d_in[3];
    const float* ln_ffn_w    = (const float*)d_in[4];
    const float* ln_ffn_b    = (const float*)d_in[5];
    const float* qkv_w       = (const float*)d_in[6];
    const float* qkv_dw_w    = (const float*)d_in[7];
    const float* temperature = (const float*)d_in[8];
    const float* proj_attn_w = (const float*)d_in[9];
    const float* ffn_in_w    = (const float*)d_in[10];
    const float* ffn_dw_w    = (const float*)d_in[11];
    const float* ffn_out_w   = (const float*)d_in[12];
    const float* proj3d_w    = (const float*)d_in[13];

    char* wsb = (char*)d_ws;
    short* Wbf     = (short*)wsb;                 // 287744 bf16 weights
    short* mlpW    = Wbf;                         // [128][640] tap-major
    short* qkvW    = Wbf + 81920;                 // [384][128]
    short* projW   = Wbf + 131072;                // [128][128]
    short* ffnInW  = Wbf + 147456;                // [680][128]
    short* ffnOutW = Wbf + 234496;                // [128][352] (padded)
    short* p3dW    = Wbf + 279552;                // [64][128]
    float* wqT     = (float*)(wsb + 575488);      // [9][384] f32
    float* wgT     = (float*)(wsb + 589312);      // [9][680] f32
    float* tok     = (float*)(wsb + 33381792);    // [M][128] f32
    short* LNbf    = (short*)(wsb + 46488992);    // [M][128] bf16
    short* QKVpre  = (short*)(wsb + 53042592);    // [M][384] bf16
    short* qkvb    = (short*)(wsb + 72703392);    // [M][384] bf16
    short* AObf    = (short*)(wsb + 92364192);    // [M][128] bf16
    short* F1      = (short*)(wsb + 98917792);    // [M][680] bf16
    short* G       = (short*)(wsb + 133733792);   // [M][352] bf16 (padded)

    dim3 blk(256);

    prep_k<<<1162, blk, 0, stream>>>(mlp_w, qkv_w, proj_attn_w, ffn_in_w, ffn_out_w, proj3d_w,
                                     qkv_dw_w, ffn_dw_w, Wbf, wqT, wgT);

    // S2T: tok = im2col(buffer) @ mlp_w^T — fused im2col, 2-deep prefetch
    mmim_k<<<dim3(200, 2), blk, 0, stream>>>(buffer, mlpW, tok);
    ln_k<<<6400, blk, 0, stream>>>(tok, ln_attn_w, ln_attn_b, LNbf);
    // qkv 1x1 (bf16 out) — WIDE tile, 2-deep prefetch
    mmw_k<<<dim3(200, 3), blk, 0, stream>>>(LNbf, qkvW, QKVpre, M_TOK, 384, 128);
    // fused dwconv + l2norm + temperature fold
    dwl2n_k<<<4800, blk, 0, stream>>>(QKVpre, wqT, temperature, qkvb);
    // attention v9 (r16 structure + setprio)
    attn_k<<<1600, blk, 0, stream>>>(qkvb, AObf);
    // proj + residual — 64x64 tiles
    mm64_k<true, false, false><<<dim3(400, 2), blk, 0, stream>>>(AObf, projW, tok, M_TOK, 128, 128);
    ln_k<<<6400, blk, 0, stream>>>(tok, ln_ffn_w, ln_ffn_b, LNbf);
    // ffn_in 1x1 (bf16 out) — WIDE tile, 2-deep prefetch
    mmw_k<<<dim3(200, 6), blk, 0, stream>>>(LNbf, ffnInW, F1, M_TOK, 680, 128);
    // fused GDFN dwconv + gelu gate -> G [M][352] (padded)
    gdfn2_k<<<4400, blk, 0, stream>>>(F1, wgT, G);
    // ffn_out + residual, K=352 — 64x64 tiles
    mm64_k<true, false, false><<<dim3(400, 2), blk, 0, stream>>>(G, ffnOutW, tok, M_TOK, 128, 352);
    // Token2SAI (transposed product) — 64x64 tiles
    mm64_k<false, true, true><<<dim3(400, 1), blk, 0, stream>>>(tok, p3dW, (float*)d_out, M_TOK, 64, 128);
}

// Round 19
// 183.529 us; speedup vs baseline: 1.1276x; 1.0973x over previous
//
#include <hip/hip_runtime.h>
#include <math.h>

#define M_TOK 25600   // 25 images * 1024 tokens

typedef __attribute__((ext_vector_type(8))) short bf16x8;
typedef __attribute__((ext_vector_type(4))) float f32x4;
typedef __attribute__((ext_vector_type(4))) int   i32x4;
typedef __attribute__((ext_vector_type(2))) int   i32x2;

__device__ __forceinline__ unsigned short f2b(float x) {
    unsigned u = __builtin_bit_cast(unsigned, x);
    return (unsigned short)((u + 0x7fffu + ((u >> 16) & 1u)) >> 16);
}
__device__ __forceinline__ float b2f(unsigned short h) {
    unsigned u = ((unsigned)h) << 16;
    return __builtin_bit_cast(float, u);
}
__device__ __forceinline__ unsigned cvtpk(float lo, float hi) {
    unsigned r;
    asm("v_cvt_pk_bf16_f32 %0, %1, %2" : "=v"(r) : "v"(lo), "v"(hi));
    return r;
}

// ---------------------------------------------------------------------------
// Merged prep (r14 verbatim): weight fp32->bf16 + dw-weight transposes.
// ---------------------------------------------------------------------------
__global__ __launch_bounds__(256) void prep_k(const float* __restrict__ s0, const float* __restrict__ s1,
                                              const float* __restrict__ s2, const float* __restrict__ s3,
                                              const float* __restrict__ s4, const float* __restrict__ s5,
                                              const float* __restrict__ qw, const float* __restrict__ fw,
                                              short* __restrict__ dst,
                                              float* __restrict__ wqT, float* __restrict__ wgT) {
    int i = blockIdx.x * 256 + threadIdx.x;      // < 297320
    if (i >= 297320) return;
    if (i < 287744) {
        if (i < 81920) {
            int r = i % 640, d = i / 640;        // k = tap*64 + cc (tap-major)
            int tap = r >> 6, cc = r & 63;
            dst[i] = (tap < 9) ? (short)f2b(s0[(d * 64 + cc) * 9 + tap]) : (short)0;
            return;
        }
        if (i >= 234496 && i < 279552) {         // ffn_out padded [128][352]
            int l = i - 234496;
            int row = l / 352, col = l % 352;
            dst[i] = (col < 340) ? (short)f2b(s4[row * 340 + col]) : (short)0;
            return;
        }
        const float* s; int off;
        if      (i < 131072) { s = s1; off = i - 81920; }
        else if (i < 147456) { s = s2; off = i - 131072; }
        else if (i < 234496) { s = s3; off = i - 147456; }
        else                 { s = s5; off = i - 279552; }
        dst[i] = (short)f2b(s[off]);
        return;
    }
    int j = i - 287744;                          // < 9576
    if (j < 3456) {
        int tap = j / 384, c = j % 384;
        wqT[j] = qw[c * 9 + tap];
    } else {
        int k = j - 3456;
        int tap = k / 680, c = k % 680;
        wgT[k] = fw[c * 9 + tap];
    }
}

// ---------------------------------------------------------------------------
// bf16 MFMA GEMM, 64x64 tile (r16 verbatim, PROVEN). Used for ffn_out + t2s.
// ---------------------------------------------------------------------------
template <bool ADD, bool TROUT, bool AF32>
__global__ __launch_bounds__(256) void mm64_k(const void* __restrict__ Avp,
                                              const short* __restrict__ W,
                                              float* __restrict__ outp,
                                              int M, int N, int K) {
    __shared__ __align__(16) short As[2][64 * 40];
    __shared__ __align__(16) short Bs[2][64 * 40];
    const int tid = threadIdx.x;
    const int bm = blockIdx.x * 64;
    const int bn = blockIdx.y * 64;
    const int w = tid >> 6, lane = tid & 63;
    const int h = lane >> 4, l15 = lane & 15;
    const int wm = (w >> 1) * 32, wn = (w & 1) * 32;

    const int row = tid >> 2, c4 = tid & 3;
    const int gnW = bn + row;

    f32x4 acc[2][2];
#pragma unroll
    for (int i = 0; i < 2; ++i)
#pragma unroll
        for (int j = 0; j < 2; ++j) acc[i][j] = (f32x4){0.f, 0.f, 0.f, 0.f};

    short av[8], wv[8];

    auto ldA = [&](int k0, short* tmp) {
        int gk = k0 + c4 * 8;
        size_t abase = (size_t)(bm + row) * K + gk;
        if (AF32) {
            const float* ap = (const float*)Avp + abase;
            float4 va = *(const float4*)ap;
            float4 vb = *(const float4*)(ap + 4);
            tmp[0] = (short)f2b(va.x); tmp[1] = (short)f2b(va.y);
            tmp[2] = (short)f2b(va.z); tmp[3] = (short)f2b(va.w);
            tmp[4] = (short)f2b(vb.x); tmp[5] = (short)f2b(vb.y);
            tmp[6] = (short)f2b(vb.z); tmp[7] = (short)f2b(vb.w);
        } else {
            const short* ap = (const short*)Avp + abase;
            i32x2 a = *(const i32x2*)ap;
            i32x2 b = *(const i32x2*)(ap + 4);
            *(i32x2*)&tmp[0] = a; *(i32x2*)&tmp[4] = b;
        }
    };
    auto ldW = [&](int k0, short* tmp) {
        const short* wp = W + (size_t)gnW * K + k0 + c4 * 8;
        i32x2 a = *(const i32x2*)wp;
        i32x2 b = *(const i32x2*)(wp + 4);
        *(i32x2*)&tmp[0] = a; *(i32x2*)&tmp[4] = b;
    };

    ldA(0, av);
    ldW(0, wv);

    int ph = 0;
    for (int k0 = 0; k0 < K; k0 += 32, ph ^= 1) {
        *(i32x4*)&As[ph][row * 40 + c4 * 8] = *(i32x4*)av;
        *(i32x4*)&Bs[ph][row * 40 + c4 * 8] = *(i32x4*)wv;
        if (k0 + 32 < K) {
            ldA(k0 + 32, av);
            ldW(k0 + 32, wv);
        }
        __syncthreads();

        bf16x8 af[2], bf[2];
#pragma unroll
        for (int mi = 0; mi < 2; ++mi) af[mi] = *(const bf16x8*)&As[ph][(wm + mi * 16 + l15) * 40 + h * 8];
#pragma unroll
        for (int nj = 0; nj < 2; ++nj) bf[nj] = *(const bf16x8*)&Bs[ph][(wn + nj * 16 + l15) * 40 + h * 8];
#pragma unroll
        for (int mi = 0; mi < 2; ++mi)
#pragma unroll
            for (int nj = 0; nj < 2; ++nj) {
                if (TROUT)
                    acc[mi][nj] = __builtin_amdgcn_mfma_f32_16x16x32_bf16(bf[nj], af[mi], acc[mi][nj], 0, 0, 0);
                else
                    acc[mi][nj] = __builtin_amdgcn_mfma_f32_16x16x32_bf16(af[mi], bf[nj], acc[mi][nj], 0, 0, 0);
            }
    }

    if (!TROUT) {
#pragma unroll
        for (int mi = 0; mi < 2; ++mi) {
#pragma unroll
            for (int nj = 0; nj < 2; ++nj) {
                int gn = bn + wn + nj * 16 + l15;
#pragma unroll
                for (int r = 0; r < 4; ++r) {
                    int gm = bm + wm + mi * 16 + h * 4 + r;
                    size_t oi = (size_t)gm * N + gn;
                    if (ADD) outp[oi] += acc[mi][nj][r];
                    else     outp[oi] = acc[mi][nj][r];
                }
            }
        }
    } else {
#pragma unroll
        for (int mi = 0; mi < 2; ++mi) {
            int gm = bm + wm + mi * 16 + l15;
#pragma unroll
            for (int nj = 0; nj < 2; ++nj)
#pragma unroll
                for (int r = 0; r < 4; ++r) {
                    int gn = bn + wn + nj * 16 + h * 4 + r;
                    outp[(size_t)gn * M + gm] = acc[mi][nj][r];
                }
        }
    }
}

// ---------------------------------------------------------------------------
// NEW: S2T GEMM (fused im2col) + LN(attn) epilogue. 64x128 tile (full N per
// block, 400 blocks), 4 waves 2x2 each 32x64 (acc[2][4]), 2-deep prefetch.
// Per-row LN: in-wave shfl partials + 1KB LDS cross-wave combine.
// Writes tok f32 AND LNbf bf16.
// ---------------------------------------------------------------------------
__global__ __launch_bounds__(256) void mmim_ln_k(const float* __restrict__ buf,
                                                 const short* __restrict__ W,
                                                 const float* __restrict__ lnw,
                                                 const float* __restrict__ lnb,
                                                 float* __restrict__ tok,
                                                 short* __restrict__ lnout) {
    const int K = 640;
    __shared__ __align__(16) short As[2][64 * 40];
    __shared__ __align__(16) short Bs[2][128 * 40];
    __shared__ float lnbuf[64][2][2];
    const int tid = threadIdx.x;
    const int bm = blockIdx.x * 64;
    const int w = tid >> 6, lane = tid & 63;
    const int h = lane >> 4, l15 = lane & 15;
    const int wr = w >> 1, wc = w & 1;
    const int wm = wr * 32, wn = wc * 64;

    const int rowA = tid >> 2, c4 = tid & 3;     // A: 64 rows, 1 chunk/thread
    const int rowB1 = rowA + 64;                 // B: 128 rows, 2 chunks/thread

    f32x4 acc[2][4];
#pragma unroll
    for (int i = 0; i < 2; ++i)
#pragma unroll
        for (int j = 0; j < 4; ++j) acc[i][j] = (f32x4){0.f, 0.f, 0.f, 0.f};

    auto ldA = [&](int k0, short* tmp) {         // im2col gather, token bm+rowA
        int t = bm + rowA;
        int l = t & 1023, n = t >> 10;
        int y = l >> 5, x = l & 31;
        int k = k0 + c4 * 8;
        int tap = k >> 6, cc0 = k & 63;
        bool ok = (tap < 9);
        int ti = 0, tj = 0;
        if (ok) { ti = tap / 3; tj = tap - ti * 3; }
        int yy = y + ti - 1, xx = x + tj - 1;
        ok = ok && (yy >= 0) && (yy < 32) && (xx >= 0) && (xx < 32);
        if (ok) {
            const float* bp = buf + (size_t)cc0 * M_TOK + (n << 10) + (yy << 5) + xx;
#pragma unroll
            for (int i = 0; i < 8; ++i) tmp[i] = (short)f2b(bp[(size_t)i * M_TOK]);
        } else {
#pragma unroll
            for (int i = 0; i < 8; ++i) tmp[i] = 0;
        }
    };
    auto ldW = [&](int row, int k0, short* tmp) {
        const short* wp = W + (size_t)row * K + k0 + c4 * 8;
        i32x2 a = *(const i32x2*)wp;
        i32x2 b = *(const i32x2*)(wp + 4);
        *(i32x2*)&tmp[0] = a; *(i32x2*)&tmp[4] = b;
    };
    auto compute = [&](int ph) {
        bf16x8 af[2], bf[4];
#pragma unroll
        for (int mi = 0; mi < 2; ++mi) af[mi] = *(const bf16x8*)&As[ph][(wm + mi * 16 + l15) * 40 + h * 8];
#pragma unroll
        for (int nj = 0; nj < 4; ++nj) bf[nj] = *(const bf16x8*)&Bs[ph][(wn + nj * 16 + l15) * 40 + h * 8];
#pragma unroll
        for (int mi = 0; mi < 2; ++mi)
#pragma unroll
            for (int nj = 0; nj < 4; ++nj)
                acc[mi][nj] = __builtin_amdgcn_mfma_f32_16x16x32_bf16(af[mi], bf[nj], acc[mi][nj], 0, 0, 0);
    };

    short aA[8], b0A[8], b1A[8];
    short aB[8], b0B[8], b1B[8];
    ldA(0, aA);  ldW(rowA, 0, b0A);  ldW(rowB1, 0, b1A);
    ldA(32, aB); ldW(rowA, 32, b0B); ldW(rowB1, 32, b1B);

    for (int k0 = 0; k0 < K; k0 += 64) {
        *(i32x4*)&As[0][rowA * 40 + c4 * 8]  = *(i32x4*)aA;
        *(i32x4*)&Bs[0][rowA * 40 + c4 * 8]  = *(i32x4*)b0A;
        *(i32x4*)&Bs[0][rowB1 * 40 + c4 * 8] = *(i32x4*)b1A;
        if (k0 + 64 < K) { ldA(k0 + 64, aA); ldW(rowA, k0 + 64, b0A); ldW(rowB1, k0 + 64, b1A); }
        __syncthreads();
        compute(0);
        *(i32x4*)&As[1][rowA * 40 + c4 * 8]  = *(i32x4*)aB;
        *(i32x4*)&Bs[1][rowA * 40 + c4 * 8]  = *(i32x4*)b0B;
        *(i32x4*)&Bs[1][rowB1 * 40 + c4 * 8] = *(i32x4*)b1B;
        if (k0 + 96 < K) { ldA(k0 + 96, aB); ldW(rowA, k0 + 96, b0B); ldW(rowB1, k0 + 96, b1B); }
        __syncthreads();
        compute(1);
    }

    // ---- LN epilogue ----
#pragma unroll
    for (int mi = 0; mi < 2; ++mi)
#pragma unroll
        for (int rr = 0; rr < 4; ++rr) {
            float s = 0.f, q = 0.f;
#pragma unroll
            for (int nj = 0; nj < 4; ++nj) {
                float v = acc[mi][nj][rr];
                s += v; q += v * v;
            }
#pragma unroll
            for (int off = 1; off < 16; off <<= 1) {
                s += __shfl_xor(s, off);
                q += __shfl_xor(q, off);
            }
            if (l15 == 0) {
                int rl = wm + mi * 16 + h * 4 + rr;
                lnbuf[rl][wc][0] = s;
                lnbuf[rl][wc][1] = q;
            }
        }
    __syncthreads();

    float wl[4], bl[4];
#pragma unroll
    for (int nj = 0; nj < 4; ++nj) {
        int gn = wn + nj * 16 + l15;
        wl[nj] = lnw[gn];
        bl[nj] = lnb[gn];
    }
#pragma unroll
    for (int mi = 0; mi < 2; ++mi)
#pragma unroll
        for (int rr = 0; rr < 4; ++rr) {
            int rl = wm + mi * 16 + h * 4 + rr;
            int gm = bm + rl;
            float S = lnbuf[rl][0][0] + lnbuf[rl][1][0];
            float Q = lnbuf[rl][0][1] + lnbuf[rl][1][1];
            float mean = S * (1.f / 128.f);
            float var = Q * (1.f / 128.f) - mean * mean;
            float rstd = rsqrtf(var + 1e-5f);
#pragma unroll
            for (int nj = 0; nj < 4; ++nj) {
                int gn = wn + nj * 16 + l15;
                float v = acc[mi][nj][rr];
                tok[(size_t)gm * 128 + gn] = v;
                float o = (v - mean) * rstd * wl[nj] + bl[nj];
                lnout[(size_t)gm * 128 + gn] = (short)f2b(o);
            }
        }
}

// ---------------------------------------------------------------------------
// NEW: proj GEMM + residual + LN(ffn) epilogue. 64x128 tile, 400 blocks,
// K=128. A = AObf bf16. Updates tok f32 (residual) AND writes LNbf bf16.
// ---------------------------------------------------------------------------
__global__ __launch_bounds__(256) void pmln_k(const short* __restrict__ A,
                                              const short* __restrict__ W,
                                              const float* __restrict__ lnw,
                                              const float* __restrict__ lnb,
                                              float* __restrict__ tok,
                                              short* __restrict__ lnout) {
    const int K = 128;
    __shared__ __align__(16) short As[2][64 * 40];
    __shared__ __align__(16) short Bs[2][128 * 40];
    __shared__ float lnbuf[64][2][2];
    const int tid = threadIdx.x;
    const int bm = blockIdx.x * 64;
    const int w = tid >> 6, lane = tid & 63;
    const int h = lane >> 4, l15 = lane & 15;
    const int wr = w >> 1, wc = w & 1;
    const int wm = wr * 32, wn = wc * 64;

    const int rowA = tid >> 2, c4 = tid & 3;
    const int rowB1 = rowA + 64;

    f32x4 acc[2][4];
#pragma unroll
    for (int i = 0; i < 2; ++i)
#pragma unroll
        for (int j = 0; j < 4; ++j) acc[i][j] = (f32x4){0.f, 0.f, 0.f, 0.f};

    auto ldA = [&](int k0, short* tmp) {
        const short* ap = A + (size_t)(bm + rowA) * K + k0 + c4 * 8;
        i32x2 a = *(const i32x2*)ap;
        i32x2 b = *(const i32x2*)(ap + 4);
        *(i32x2*)&tmp[0] = a; *(i32x2*)&tmp[4] = b;
    };
    auto ldW = [&](int row, int k0, short* tmp) {
        const short* wp = W + (size_t)row * K + k0 + c4 * 8;
        i32x2 a = *(const i32x2*)wp;
        i32x2 b = *(const i32x2*)(wp + 4);
        *(i32x2*)&tmp[0] = a; *(i32x2*)&tmp[4] = b;
    };
    auto compute = [&](int ph) {
        bf16x8 af[2], bf[4];
#pragma unroll
        for (int mi = 0; mi < 2; ++mi) af[mi] = *(const bf16x8*)&As[ph][(wm + mi * 16 + l15) * 40 + h * 8];
#pragma unroll
        for (int nj = 0; nj < 4; ++nj) bf[nj] = *(const bf16x8*)&Bs[ph][(wn + nj * 16 + l15) * 40 + h * 8];
#pragma unroll
        for (int mi = 0; mi < 2; ++mi)
#pragma unroll
            for (int nj = 0; nj < 4; ++nj)
                acc[mi][nj] = __builtin_amdgcn_mfma_f32_16x16x32_bf16(af[mi], bf[nj], acc[mi][nj], 0, 0, 0);
    };

    short aA[8], b0A[8], b1A[8];
    short aB[8], b0B[8], b1B[8];
    ldA(0, aA);  ldW(rowA, 0, b0A);  ldW(rowB1, 0, b1A);
    ldA(32, aB); ldW(rowA, 32, b0B); ldW(rowB1, 32, b1B);

    for (int k0 = 0; k0 < K; k0 += 64) {
        *(i32x4*)&As[0][rowA * 40 + c4 * 8]  = *(i32x4*)aA;
        *(i32x4*)&Bs[0][rowA * 40 + c4 * 8]  = *(i32x4*)b0A;
        *(i32x4*)&Bs[0][rowB1 * 40 + c4 * 8] = *(i32x4*)b1A;
        if (k0 + 64 < K) { ldA(k0 + 64, aA); ldW(rowA, k0 + 64, b0A); ldW(rowB1, k0 + 64, b1A); }
        __syncthreads();
        compute(0);
        *(i32x4*)&As[1][rowA * 40 + c4 * 8]  = *(i32x4*)aB;
        *(i32x4*)&Bs[1][rowA * 40 + c4 * 8]  = *(i32x4*)b0B;
        *(i32x4*)&Bs[1][rowB1 * 40 + c4 * 8] = *(i32x4*)b1B;
        if (k0 + 96 < K) { ldA(k0 + 96, aB); ldW(rowA, k0 + 96, b0B); ldW(rowB1, k0 + 96, b1B); }
        __syncthreads();
        compute(1);
    }

    // ---- residual add (into acc), then LN epilogue ----
#pragma unroll
    for (int mi = 0; mi < 2; ++mi)
#pragma unroll
        for (int rr = 0; rr < 4; ++rr) {
            int gm = bm + wm + mi * 16 + h * 4 + rr;
#pragma unroll
            for (int nj = 0; nj < 4; ++nj) {
                int gn = wn + nj * 16 + l15;
                acc[mi][nj][rr] += tok[(size_t)gm * 128 + gn];
            }
        }
#pragma unroll
    for (int mi = 0; mi < 2; ++mi)
#pragma unroll
        for (int rr = 0; rr < 4; ++rr) {
            float s = 0.f, q = 0.f;
#pragma unroll
            for (int nj = 0; nj < 4; ++nj) {
                float v = acc[mi][nj][rr];
                s += v; q += v * v;
            }
#pragma unroll
            for (int off = 1; off < 16; off <<= 1) {
                s += __shfl_xor(s, off);
                q += __shfl_xor(q, off);
            }
            if (l15 == 0) {
                int rl = wm + mi * 16 + h * 4 + rr;
                lnbuf[rl][wc][0] = s;
                lnbuf[rl][wc][1] = q;
            }
        }
    __syncthreads();

    float wl[4], bl[4];
#pragma unroll
    for (int nj = 0; nj < 4; ++nj) {
        int gn = wn + nj * 16 + l15;
        wl[nj] = lnw[gn];
        bl[nj] = lnb[gn];
    }
#pragma unroll
    for (int mi = 0; mi < 2; ++mi)
#pragma unroll
        for (int rr = 0; rr < 4; ++rr) {
            int rl = wm + mi * 16 + h * 4 + rr;
            int gm = bm + rl;
            float S = lnbuf[rl][0][0] + lnbuf[rl][1][0];
            float Q = lnbuf[rl][0][1] + lnbuf[rl][1][1];
            float mean = S * (1.f / 128.f);
            float var = Q * (1.f / 128.f) - mean * mean;
            float rstd = rsqrtf(var + 1e-5f);
#pragma unroll
            for (int nj = 0; nj < 4; ++nj) {
                int gn = wn + nj * 16 + l15;
                float v = acc[mi][nj][rr];
                tok[(size_t)gm * 128 + gn] = v;
                float o = (v - mean) * rstd * wl[nj] + bl[nj];
                lnout[(size_t)gm * 128 + gn] = (short)f2b(o);
            }
        }
}

// ---------------------------------------------------------------------------
// bf16 MFMA GEMM WIDE (r15 verbatim): 128x128 tile + 2-deep prefetch.
// ---------------------------------------------------------------------------
__global__ __launch_bounds__(256) void mmw_k(const short* __restrict__ A,
                                             const short* __restrict__ W,
                                             short* __restrict__ outp,
                                             int M, int N, int K) {
    __shared__ __align__(16) short As[2][128 * 40];
    __shared__ __align__(16) short Bs[2][128 * 40];
    const int tid = threadIdx.x;
    const int bm = blockIdx.x * 128;
    const int bn = blockIdx.y * 128;
    const int w = tid >> 6, lane = tid & 63;
    const int h = lane >> 4, l15 = lane & 15;
    const int wm = (w >> 1) * 64, wn = (w & 1) * 64;

    const int row0 = tid >> 2, c4 = tid & 3;
    const int row1 = row0 + 64;

    f32x4 acc[4][4];
#pragma unroll
    for (int i = 0; i < 4; ++i)
#pragma unroll
        for (int j = 0; j < 4; ++j) acc[i][j] = (f32x4){0.f, 0.f, 0.f, 0.f};

    auto ldA = [&](int row, int k0, short* tmp) {
        const short* ap = A + (size_t)(bm + row) * K + k0 + c4 * 8;
        i32x2 x = *(const i32x2*)ap;
        i32x2 y = *(const i32x2*)(ap + 4);
        *(i32x2*)&tmp[0] = x; *(i32x2*)&tmp[4] = y;
    };
    auto ldW = [&](int row, int k0, short* tmp) {
        int gn = bn + row;
        if (gn < N) {
            const short* wp = W + (size_t)gn * K + k0 + c4 * 8;
            i32x2 x = *(const i32x2*)wp;
            i32x2 y = *(const i32x2*)(wp + 4);
            *(i32x2*)&tmp[0] = x; *(i32x2*)&tmp[4] = y;
        } else {
#pragma unroll
            for (int i = 0; i < 8; ++i) tmp[i] = 0;
        }
    };
    auto compute = [&](int ph) {
        bf16x8 af[4], bf[4];
#pragma unroll
        for (int mi = 0; mi < 4; ++mi) af[mi] = *(const bf16x8*)&As[ph][(wm + mi * 16 + l15) * 40 + h * 8];
#pragma unroll
        for (int nj = 0; nj < 4; ++nj) bf[nj] = *(const bf16x8*)&Bs[ph][(wn + nj * 16 + l15) * 40 + h * 8];
#pragma unroll
        for (int mi = 0; mi < 4; ++mi)
#pragma unroll
            for (int nj = 0; nj < 4; ++nj)
                acc[mi][nj] = __builtin_amdgcn_mfma_f32_16x16x32_bf16(af[mi], bf[nj], acc[mi][nj], 0, 0, 0);
    };

    short a0A[8], a1A[8], b0A[8], b1A[8];
    short a0B[8], a1B[8], b0B[8], b1B[8];
    ldA(row0, 0, a0A);  ldA(row1, 0, a1A);  ldW(row0, 0, b0A);  ldW(row1, 0, b1A);
    ldA(row0, 32, a0B); ldA(row1, 32, a1B); ldW(row0, 32, b0B); ldW(row1, 32, b1B);

    for (int k0 = 0; k0 < K; k0 += 64) {
        *(i32x4*)&As[0][row0 * 40 + c4 * 8] = *(i32x4*)a0A;
        *(i32x4*)&As[0][row1 * 40 + c4 * 8] = *(i32x4*)a1A;
        *(i32x4*)&Bs[0][row0 * 40 + c4 * 8] = *(i32x4*)b0A;
        *(i32x4*)&Bs[0][row1 * 40 + c4 * 8] = *(i32x4*)b1A;
        if (k0 + 64 < K) {
            ldA(row0, k0 + 64, a0A); ldA(row1, k0 + 64, a1A);
            ldW(row0, k0 + 64, b0A); ldW(row1, k0 + 64, b1A);
        }
        __syncthreads();
        compute(0);
        *(i32x4*)&As[1][row0 * 40 + c4 * 8] = *(i32x4*)a0B;
        *(i32x4*)&As[1][row1 * 40 + c4 * 8] = *(i32x4*)a1B;
        *(i32x4*)&Bs[1][row0 * 40 + c4 * 8] = *(i32x4*)b0B;
        *(i32x4*)&Bs[1][row1 * 40 + c4 * 8] = *(i32x4*)b1B;
        if (k0 + 96 < K) {
            ldA(row0, k0 + 96, a0B); ldA(row1, k0 + 96, a1B);
            ldW(row0, k0 + 96, b0B); ldW(row1, k0 + 96, b1B);
        }
        __syncthreads();
        compute(1);
    }

#pragma unroll
    for (int mi = 0; mi < 4; ++mi) {
#pragma unroll
        for (int nj = 0; nj < 4; ++nj) {
            int gn = bn + wn + nj * 16 + l15;
            if (gn < N) {
#pragma unroll
                for (int r = 0; r < 4; ++r) {
                    int gm = bm + wm + mi * 16 + h * 4 + r;
                    outp[(size_t)gm * N + gn] = (short)f2b(acc[mi][nj][r]);
                }
            }
        }
    }
}

// ---------------------------------------------------------------------------
// Fused qkv depthwise 3x3 + l2norm(q,k) + temperature*log2e folded into q.
// ---------------------------------------------------------------------------
__global__ __launch_bounds__(256) void dwl2n_k(const short* __restrict__ in,
                                               const float* __restrict__ wqT,
                                               const float* __restrict__ temp,
                                               short* __restrict__ out) {
    int idx = blockIdx.x * 256 + threadIdx.x;    // < M*48
    int q = idx % 48;
    int t = idx / 48;
    int c0 = q * 8;
    int l = t & 1023, n = t >> 10;
    int y = l >> 5, x = l & 31;
    int tb = n << 10;

    float acc[8];
#pragma unroll
    for (int k = 0; k < 8; ++k) acc[k] = 0.f;

#pragma unroll
    for (int i = 0; i < 3; ++i) {
        int yy = y + i - 1;
        if (yy < 0 || yy >= 32) continue;
#pragma unroll
        for (int j = 0; j < 3; ++j) {
            int xx = x + j - 1;
            if (xx < 0 || xx >= 32) continue;
            bf16x8 d = *(const bf16x8*)(in + (size_t)(tb + (yy << 5) + xx) * 384 + c0);
            float4 wa = *(const float4*)(wqT + (i * 3 + j) * 384 + c0);
            float4 wb = *(const float4*)(wqT + (i * 3 + j) * 384 + c0 + 4);
            acc[0] += b2f((unsigned short)d[0]) * wa.x;
            acc[1] += b2f((unsigned short)d[1]) * wa.y;
            acc[2] += b2f((unsigned short)d[2]) * wa.z;
            acc[3] += b2f((unsigned short)d[3]) * wa.w;
            acc[4] += b2f((unsigned short)d[4]) * wb.x;
            acc[5] += b2f((unsigned short)d[5]) * wb.y;
            acc[6] += b2f((unsigned short)d[6]) * wb.z;
            acc[7] += b2f((unsigned short)d[7]) * wb.w;
        }
    }
    float ss = 0.f;
#pragma unroll
    for (int k = 0; k < 8; ++k) ss += acc[k] * acc[k];
    ss += __shfl_xor(ss, 1);
    ss += __shfl_xor(ss, 2);
    float sc;
    if (c0 < 128)       sc = (1.f / fmaxf(sqrtf(ss), 1e-12f)) * temp[c0 >> 5] * 1.44269504089f;
    else if (c0 < 256)  sc = 1.f / fmaxf(sqrtf(ss), 1e-12f);
    else                sc = 1.f;
    unsigned o[4];
#pragma unroll
    for (int k = 0; k < 4; ++k)
        o[k] = f2b(acc[2 * k] * sc) | ((unsigned)f2b(acc[2 * k + 1] * sc) << 16);
    *(i32x4*)(out + (size_t)t * 384 + c0) = *(i32x4*)o;
}

// ---------------------------------------------------------------------------
// Fused GDFN depthwise: dual 3x3 dwconv + exact gelu gate. out [M][352].
// ---------------------------------------------------------------------------
__global__ __launch_bounds__(256) void gdfn2_k(const short* __restrict__ in,
                                               const float* __restrict__ wgT,
                                               short* __restrict__ out) {
    int idx = blockIdx.x * 256 + threadIdx.x;    // < M*44
    int q = idx % 44;
    int t = idx / 44;
    int c0 = q * 8;
    short* op = out + (size_t)t * 352 + c0;
    if (q == 43) {
        *(i32x4*)op = (i32x4){0, 0, 0, 0};
        return;
    }
    int l = t & 1023, n = t >> 10;
    int y = l >> 5, x = l & 31;
    int tb = n << 10;

    float a[8], g[8];
#pragma unroll
    for (int k = 0; k < 8; ++k) { a[k] = 0.f; g[k] = 0.f; }

#pragma unroll
    for (int i = 0; i < 3; ++i) {
        int yy = y + i - 1;
        if (yy < 0 || yy >= 32) continue;
#pragma unroll
        for (int j = 0; j < 3; ++j) {
            int xx = x + j - 1;
            if (xx < 0 || xx >= 32) continue;
            const short* p = in + (size_t)(tb + (yy << 5) + xx) * 680 + c0;
            bf16x8 d1 = *(const bf16x8*)p;
            i32x2 d2a = *(const i32x2*)(p + 340);
            i32x2 d2b = *(const i32x2*)(p + 344);
            short d2[8];
            *(i32x2*)&d2[0] = d2a; *(i32x2*)&d2[4] = d2b;
            const float* wp = wgT + (i * 3 + j) * 680 + c0;
            float4 w1a = *(const float4*)wp;
            float4 w1b = *(const float4*)(wp + 4);
            float w1[8] = {w1a.x, w1a.y, w1a.z, w1a.w, w1b.x, w1b.y, w1b.z, w1b.w};
            float w2[8];
#pragma unroll
            for (int k = 0; k < 8; ++k) w2[k] = wp[340 + k];
#pragma unroll
            for (int k = 0; k < 8; ++k) {
                a[k] += b2f((unsigned short)d1[k]) * w1[k];
                g[k] += b2f((unsigned short)d2[k]) * w2[k];
            }
        }
    }
    unsigned o[4];
#pragma unroll
    for (int k = 0; k < 4; ++k) {
        float r0 = 0.5f * a[2 * k] * (1.f + erff(a[2 * k] * 0.70710678118f)) * g[2 * k];
        float r1 = 0.5f * a[2 * k + 1] * (1.f + erff(a[2 * k + 1] * 0.70710678118f)) * g[2 * k + 1];
        o[k] = f2b(r0) | ((unsigned)f2b(r1) << 16);
    }
    if (q == 42) { o[2] = 0; o[3] = 0; }
    *(i32x4*)op = *(i32x4*)o;
}

// ---------------------------------------------------------------------------
// MFMA flash attention v9 (r18 verbatim — PROVEN at ~43.5us).
// ---------------------------------------------------------------------------
__global__ __launch_bounds__(256) void attn_k(const short* __restrict__ qkv,
                                              short* __restrict__ outp) {
    __shared__ __align__(16) short Ks[2][64 * 40];
    __shared__ __align__(16) short Vp[2][2048];
    const int b = blockIdx.x;
    const int orig = (b & 7) * 200 + (b >> 3);   // XCD-contiguous remap
    const int qt = orig & 15, nh = orig >> 4;
    const int hd = nh & 3, n = nh >> 2;
    const int tid = threadIdx.x;
    const int w = tid >> 6, lane = tid & 63;
    const int h = lane >> 4, l15 = lane & 15;
    const size_t base = (size_t)n * 1024 * 384;
    const int qrow = qt * 64 + w * 16 + l15;

    bf16x8 qf = *(const bf16x8*)(qkv + base + (size_t)qrow * 384 + hd * 32 + h * 8);
    f32x4 o0 = {0.f,0.f,0.f,0.f}, o1 = {0.f,0.f,0.f,0.f};
    f32x4 osum = {0.f,0.f,0.f,0.f};
    union { unsigned u[4]; bf16x8 v; } ones;
#pragma unroll
    for (int r = 0; r < 4; ++r) ones.u[r] = 0x3F803F80u;

    const int skey = tid >> 2, sc4 = tid & 3;
    const int sg = skey >> 5, skey5 = skey & 31;
    const int sh = (skey5 >> 2) & 3;
    const int sj = (skey5 & 3) + ((skey5 >> 4) << 2);
    const int sgran0 = (sg * 4 + sh) * 32 + sc4 * 8;
    const short* kbase = qkv + base + (size_t)skey * 384 + 128 + hd * 32 + sc4 * 8;

    auto scatterV = [&](int nb, i32x4 vreg) {
        short vs[8];
        *(i32x4*)vs = vreg;
#pragma unroll
        for (int i = 0; i < 8; ++i) {
            int gran = sgran0 + i;
            gran ^= (gran >> 3) & 7;
            Vp[nb][gran * 8 + sj] = vs[i];
        }
    };
    auto compute = [&](int nb) {
        const bf16x8 kf0 = *(const bf16x8*)&Ks[nb][l15 * 40 + h * 8];
        const bf16x8 kf1 = *(const bf16x8*)&Ks[nb][(16 + l15) * 40 + h * 8];
        const bf16x8 kf2 = *(const bf16x8*)&Ks[nb][(32 + l15) * 40 + h * 8];
        const bf16x8 kf3 = *(const bf16x8*)&Ks[nb][(48 + l15) * 40 + h * 8];
        int gr0 = h * 32 + l15;            gr0 ^= (gr0 >> 3) & 7;
        int gr1 = h * 32 + 16 + l15;       gr1 ^= (gr1 >> 3) & 7;
        int gr2 = (4 + h) * 32 + l15;      gr2 ^= (gr2 >> 3) & 7;
        int gr3 = (4 + h) * 32 + 16 + l15; gr3 ^= (gr3 >> 3) & 7;
        const bf16x8 va0 = *(const bf16x8*)&Vp[nb][gr0 * 8];
        const bf16x8 va1 = *(const bf16x8*)&Vp[nb][gr1 * 8];
        const bf16x8 vb0 = *(const bf16x8*)&Vp[nb][gr2 * 8];
        const bf16x8 vb1 = *(const bf16x8*)&Vp[nb][gr3 * 8];
        const f32x4 z = {0.f, 0.f, 0.f, 0.f};

        __builtin_amdgcn_s_setprio(1);
        f32x4 s0 = __builtin_amdgcn_mfma_f32_16x16x32_bf16(kf0, qf, z, 0, 0, 0);
        f32x4 s1 = __builtin_amdgcn_mfma_f32_16x16x32_bf16(kf1, qf, z, 0, 0, 0);
        f32x4 s2 = __builtin_amdgcn_mfma_f32_16x16x32_bf16(kf2, qf, z, 0, 0, 0);
        f32x4 s3 = __builtin_amdgcn_mfma_f32_16x16x32_bf16(kf3, qf, z, 0, 0, 0);
        __builtin_amdgcn_s_setprio(0);
        float p[16];
#pragma unroll
        for (int r = 0; r < 4; ++r) {
            p[r]      = exp2f(s0[r]);
            p[4 + r]  = exp2f(s1[r]);
            p[8 + r]  = exp2f(s2[r]);
            p[12 + r] = exp2f(s3[r]);
        }
        union { unsigned u[4]; bf16x8 v; } pf1, pf2;
#pragma unroll
        for (int r = 0; r < 4; ++r) {
            pf1.u[r] = cvtpk(p[2 * r], p[2 * r + 1]);
            pf2.u[r] = cvtpk(p[8 + 2 * r], p[8 + 2 * r + 1]);
        }
        __builtin_amdgcn_s_setprio(1);
        osum = __builtin_amdgcn_mfma_f32_16x16x32_bf16(ones.v, pf1.v, osum, 0, 0, 0);
        osum = __builtin_amdgcn_mfma_f32_16x16x32_bf16(ones.v, pf2.v, osum, 0, 0, 0);
        o0 = __builtin_amdgcn_mfma_f32_16x16x32_bf16(va0, pf1.v, o0, 0, 0, 0);
        o1 = __builtin_amdgcn_mfma_f32_16x16x32_bf16(va1, pf1.v, o1, 0, 0, 0);
        o0 = __builtin_amdgcn_mfma_f32_16x16x32_bf16(vb0, pf2.v, o0, 0, 0, 0);
        o1 = __builtin_amdgcn_mfma_f32_16x16x32_bf16(vb1, pf2.v, o1, 0, 0, 0);
        __builtin_amdgcn_s_setprio(0);
    };

    i32x4 kregA = *(const i32x4*)kbase;
    i32x4 vregA = *(const i32x4*)(kbase + 128);
    i32x4 kregB = *(const i32x4*)(kbase + (size_t)64 * 384);
    i32x4 vregB = *(const i32x4*)(kbase + (size_t)64 * 384 + 128);

    for (int t = 0; t < 16; t += 2) {
        *(i32x4*)&Ks[0][skey * 40 + sc4 * 8] = kregA;
        scatterV(0, vregA);
        if (t + 2 < 16) {
            const short* kp = kbase + (size_t)(t + 2) * 64 * 384;
            kregA = *(const i32x4*)kp;
            vregA = *(const i32x4*)(kp + 128);
        }
        __syncthreads();
        compute(0);
        *(i32x4*)&Ks[1][skey * 40 + sc4 * 8] = kregB;
        scatterV(1, vregB);
        if (t + 3 < 16) {
            const short* kp = kbase + (size_t)(t + 3) * 64 * 384;
            kregB = *(const i32x4*)kp;
            vregB = *(const i32x4*)(kp + 128);
        }
        __syncthreads();
        compute(1);
    }

    float inv = 1.f / osum[0];

    size_t ob = ((size_t)n * 1024 + qrow) * 128 + hd * 32;
    unsigned u;
    u = f2b(o0[0] * inv) | ((unsigned)f2b(o0[1] * inv) << 16); *(unsigned*)(outp + ob + h * 4) = u;
    u = f2b(o0[2] * inv) | ((unsigned)f2b(o0[3] * inv) << 16); *(unsigned*)(outp + ob + h * 4 + 2) = u;
    u = f2b(o1[0] * inv) | ((unsigned)f2b(o1[1] * inv) << 16); *(unsigned*)(outp + ob + 16 + h * 4) = u;
    u = f2b(o1[2] * inv) | ((unsigned)f2b(o1[3] * inv) << 16); *(unsigned*)(outp + ob + 16 + h * 4 + 2) = u;
}

// ---------------------------------------------------------------------------
extern "C" void kernel_launch(void* const* d_in, const int* in_sizes, int n_in,
                              void* d_out, int out_size, void* d_ws, size_t ws_size,
                              hipStream_t stream) {
    const float* buffer      = (const float*)d_in[0];
    const float* mlp_w       = (const float*)d_in[1];
    const float* ln_attn_w   = (const float*)d_in[2];
    const float* ln_attn_b   = (const float*)d_in[3];
    const float* ln_ffn_w    = (const float*)d_in[4];
    const float* ln_ffn_b    = (const float*)d_in[5];
    const float* qkv_w       = (const float*)d_in[6];
    const float* qkv_dw_w    = (const float*)d_in[7];
    const float* temperature = (const float*)d_in[8];
    const float* proj_attn_w = (const float*)d_in[9];
    const float* ffn_in_w    = (const float*)d_in[10];
    const float* ffn_dw_w    = (const float*)d_in[11];
    const float* ffn_out_w   = (const float*)d_in[12];
    const float* proj3d_w    = (const float*)d_in[13];

    char* wsb = (char*)d_ws;
    short* Wbf     = (short*)wsb;                 // 287744 bf16 weights
    short* mlpW    = Wbf;                         // [128][640] tap-major
    short* qkvW    = Wbf + 81920;                 // [384][128]
    short* projW   = Wbf + 131072;                // [128][128]
    short* ffnInW  = Wbf + 147456;                // [680][128]
    short* ffnOutW = Wbf + 234496;                // [128][352] (padded)
    short* p3dW    = Wbf + 279552;                // [64][128]
    float* wqT     = (float*)(wsb + 575488);      // [9][384] f32
    float* wgT     = (float*)(wsb + 589312);      // [9][680] f32
    float* tok     = (float*)(wsb + 33381792);    // [M][128] f32
    short* LNbf    = (short*)(wsb + 46488992);    // [M][128] bf16
    short* QKVpre  = (short*)(wsb + 53042592);    // [M][384] bf16
    short* qkvb    = (short*)(wsb + 72703392);    // [M][384] bf16
    short* AObf    = (short*)(wsb + 92364192);    // [M][128] bf16
    short* F1      = (short*)(wsb + 98917792);    // [M][680] bf16
    short* G       = (short*)(wsb + 133733792);   // [M][352] bf16 (padded)

    dim3 blk(256);

    prep_k<<<1162, blk, 0, stream>>>(mlp_w, qkv_w, proj_attn_w, ffn_in_w, ffn_out_w, proj3d_w,
                                     qkv_dw_w, ffn_dw_w, Wbf, wqT, wgT);

    // S2T + LN(attn) fused: tok f32 + LNbf bf16 in one pass
    mmim_ln_k<<<400, blk, 0, stream>>>(buffer, mlpW, ln_attn_w, ln_attn_b, tok, LNbf);
    // qkv 1x1 (bf16 out) — WIDE tile, 2-deep prefetch
    mmw_k<<<dim3(200, 3), blk, 0, stream>>>(LNbf, qkvW, QKVpre, M_TOK, 384, 128);
    // fused dwconv + l2norm + temperature fold
    dwl2n_k<<<4800, blk, 0, stream>>>(QKVpre, wqT, temperature, qkvb);
    // attention v9
    attn_k<<<1600, blk, 0, stream>>>(qkvb, AObf);
    // proj + residual + LN(ffn) fused: updates tok, writes LNbf
    pmln_k<<<400, blk, 0, stream>>>(AObf, projW, ln_ffn_w, ln_ffn_b, tok, LNbf);
    // ffn_in 1x1 (bf16 out) — WIDE tile, 2-deep prefetch
    mmw_k<<<dim3(200, 6), blk, 0, stream>>>(LNbf, ffnInW, F1, M_TOK, 680, 128);
    // fused GDFN dwconv + gelu gate -> G [M][352] (padded)
    gdfn2_k<<<4400, blk, 0, stream>>>(F1, wgT, G);
    // ffn_out + residual, K=352 — 64x64 tiles
    mm64_k<true, false, false><<<dim3(400, 2), blk, 0, stream>>>(G, ffnOutW, tok, M_TOK, 128, 352);
    // Token2SAI (transposed product) — 64x64 tiles
    mm64_k<false, true, true><<<dim3(400, 1), blk, 0, stream>>>(tok, p3dW, (float*)d_out, M_TOK, 64, 128);
}

// Round 20
// 176.341 us; speedup vs baseline: 1.1736x; 1.0408x over previous
//
#include <hip/hip_runtime.h>
#include <math.h>

#define M_TOK 25600   // 25 images * 1024 tokens

typedef __attribute__((ext_vector_type(8))) short bf16x8;
typedef __attribute__((ext_vector_type(4))) float f32x4;
typedef __attribute__((ext_vector_type(4))) int   i32x4;
typedef __attribute__((ext_vector_type(2))) int   i32x2;

__device__ __forceinline__ unsigned short f2b(float x) {
    unsigned u = __builtin_bit_cast(unsigned, x);
    return (unsigned short)((u + 0x7fffu + ((u >> 16) & 1u)) >> 16);
}
__device__ __forceinline__ float b2f(unsigned short h) {
    unsigned u = ((unsigned)h) << 16;
    return __builtin_bit_cast(float, u);
}
__device__ __forceinline__ unsigned cvtpk(float lo, float hi) {
    unsigned r;
    asm("v_cvt_pk_bf16_f32 %0, %1, %2" : "=v"(r) : "v"(lo), "v"(hi));
    return r;
}

// ---------------------------------------------------------------------------
// Merged prep (r14 verbatim): weight fp32->bf16 + dw-weight transposes.
// ---------------------------------------------------------------------------
__global__ __launch_bounds__(256) void prep_k(const float* __restrict__ s0, const float* __restrict__ s1,
                                              const float* __restrict__ s2, const float* __restrict__ s3,
                                              const float* __restrict__ s4, const float* __restrict__ s5,
                                              const float* __restrict__ qw, const float* __restrict__ fw,
                                              short* __restrict__ dst,
                                              float* __restrict__ wqT, float* __restrict__ wgT) {
    int i = blockIdx.x * 256 + threadIdx.x;      // < 297320
    if (i >= 297320) return;
    if (i < 287744) {
        if (i < 81920) {
            int r = i % 640, d = i / 640;        // k = tap*64 + cc (tap-major)
            int tap = r >> 6, cc = r & 63;
            dst[i] = (tap < 9) ? (short)f2b(s0[(d * 64 + cc) * 9 + tap]) : (short)0;
            return;
        }
        if (i >= 234496 && i < 279552) {         // ffn_out padded [128][352]
            int l = i - 234496;
            int row = l / 352, col = l % 352;
            dst[i] = (col < 340) ? (short)f2b(s4[row * 340 + col]) : (short)0;
            return;
        }
        const float* s; int off;
        if      (i < 131072) { s = s1; off = i - 81920; }
        else if (i < 147456) { s = s2; off = i - 131072; }
        else if (i < 234496) { s = s3; off = i - 147456; }
        else                 { s = s5; off = i - 279552; }
        dst[i] = (short)f2b(s[off]);
        return;
    }
    int j = i - 287744;                          // < 9576
    if (j < 3456) {
        int tap = j / 384, c = j % 384;
        wqT[j] = qw[c * 9 + tap];
    } else {
        int k = j - 3456;
        int tap = k / 680, c = k % 680;
        wgT[k] = fw[c * 9 + tap];
    }
}

// ---------------------------------------------------------------------------
// S2T GEMM (fused im2col) + LN(attn) epilogue (r19 verbatim, PROVEN).
// ---------------------------------------------------------------------------
__global__ __launch_bounds__(256) void mmim_ln_k(const float* __restrict__ buf,
                                                 const short* __restrict__ W,
                                                 const float* __restrict__ lnw,
                                                 const float* __restrict__ lnb,
                                                 float* __restrict__ tok,
                                                 short* __restrict__ lnout) {
    const int K = 640;
    __shared__ __align__(16) short As[2][64 * 40];
    __shared__ __align__(16) short Bs[2][128 * 40];
    __shared__ float lnbuf[64][2][2];
    const int tid = threadIdx.x;
    const int bm = blockIdx.x * 64;
    const int w = tid >> 6, lane = tid & 63;
    const int h = lane >> 4, l15 = lane & 15;
    const int wr = w >> 1, wc = w & 1;
    const int wm = wr * 32, wn = wc * 64;

    const int rowA = tid >> 2, c4 = tid & 3;
    const int rowB1 = rowA + 64;

    f32x4 acc[2][4];
#pragma unroll
    for (int i = 0; i < 2; ++i)
#pragma unroll
        for (int j = 0; j < 4; ++j) acc[i][j] = (f32x4){0.f, 0.f, 0.f, 0.f};

    auto ldA = [&](int k0, short* tmp) {
        int t = bm + rowA;
        int l = t & 1023, n = t >> 10;
        int y = l >> 5, x = l & 31;
        int k = k0 + c4 * 8;
        int tap = k >> 6, cc0 = k & 63;
        bool ok = (tap < 9);
        int ti = 0, tj = 0;
        if (ok) { ti = tap / 3; tj = tap - ti * 3; }
        int yy = y + ti - 1, xx = x + tj - 1;
        ok = ok && (yy >= 0) && (yy < 32) && (xx >= 0) && (xx < 32);
        if (ok) {
            const float* bp = buf + (size_t)cc0 * M_TOK + (n << 10) + (yy << 5) + xx;
#pragma unroll
            for (int i = 0; i < 8; ++i) tmp[i] = (short)f2b(bp[(size_t)i * M_TOK]);
        } else {
#pragma unroll
            for (int i = 0; i < 8; ++i) tmp[i] = 0;
        }
    };
    auto ldW = [&](int row, int k0, short* tmp) {
        const short* wp = W + (size_t)row * K + k0 + c4 * 8;
        i32x2 a = *(const i32x2*)wp;
        i32x2 b = *(const i32x2*)(wp + 4);
        *(i32x2*)&tmp[0] = a; *(i32x2*)&tmp[4] = b;
    };
    auto compute = [&](int ph) {
        bf16x8 af[2], bf[4];
#pragma unroll
        for (int mi = 0; mi < 2; ++mi) af[mi] = *(const bf16x8*)&As[ph][(wm + mi * 16 + l15) * 40 + h * 8];
#pragma unroll
        for (int nj = 0; nj < 4; ++nj) bf[nj] = *(const bf16x8*)&Bs[ph][(wn + nj * 16 + l15) * 40 + h * 8];
#pragma unroll
        for (int mi = 0; mi < 2; ++mi)
#pragma unroll
            for (int nj = 0; nj < 4; ++nj)
                acc[mi][nj] = __builtin_amdgcn_mfma_f32_16x16x32_bf16(af[mi], bf[nj], acc[mi][nj], 0, 0, 0);
    };

    short aA[8], b0A[8], b1A[8];
    short aB[8], b0B[8], b1B[8];
    ldA(0, aA);  ldW(rowA, 0, b0A);  ldW(rowB1, 0, b1A);
    ldA(32, aB); ldW(rowA, 32, b0B); ldW(rowB1, 32, b1B);

    for (int k0 = 0; k0 < K; k0 += 64) {
        *(i32x4*)&As[0][rowA * 40 + c4 * 8]  = *(i32x4*)aA;
        *(i32x4*)&Bs[0][rowA * 40 + c4 * 8]  = *(i32x4*)b0A;
        *(i32x4*)&Bs[0][rowB1 * 40 + c4 * 8] = *(i32x4*)b1A;
        if (k0 + 64 < K) { ldA(k0 + 64, aA); ldW(rowA, k0 + 64, b0A); ldW(rowB1, k0 + 64, b1A); }
        __syncthreads();
        compute(0);
        *(i32x4*)&As[1][rowA * 40 + c4 * 8]  = *(i32x4*)aB;
        *(i32x4*)&Bs[1][rowA * 40 + c4 * 8]  = *(i32x4*)b0B;
        *(i32x4*)&Bs[1][rowB1 * 40 + c4 * 8] = *(i32x4*)b1B;
        if (k0 + 96 < K) { ldA(k0 + 96, aB); ldW(rowA, k0 + 96, b0B); ldW(rowB1, k0 + 96, b1B); }
        __syncthreads();
        compute(1);
    }

#pragma unroll
    for (int mi = 0; mi < 2; ++mi)
#pragma unroll
        for (int rr = 0; rr < 4; ++rr) {
            float s = 0.f, q = 0.f;
#pragma unroll
            for (int nj = 0; nj < 4; ++nj) {
                float v = acc[mi][nj][rr];
                s += v; q += v * v;
            }
#pragma unroll
            for (int off = 1; off < 16; off <<= 1) {
                s += __shfl_xor(s, off);
                q += __shfl_xor(q, off);
            }
            if (l15 == 0) {
                int rl = wm + mi * 16 + h * 4 + rr;
                lnbuf[rl][wc][0] = s;
                lnbuf[rl][wc][1] = q;
            }
        }
    __syncthreads();

    float wl[4], bl[4];
#pragma unroll
    for (int nj = 0; nj < 4; ++nj) {
        int gn = wn + nj * 16 + l15;
        wl[nj] = lnw[gn];
        bl[nj] = lnb[gn];
    }
#pragma unroll
    for (int mi = 0; mi < 2; ++mi)
#pragma unroll
        for (int rr = 0; rr < 4; ++rr) {
            int rl = wm + mi * 16 + h * 4 + rr;
            int gm = bm + rl;
            float S = lnbuf[rl][0][0] + lnbuf[rl][1][0];
            float Q = lnbuf[rl][0][1] + lnbuf[rl][1][1];
            float mean = S * (1.f / 128.f);
            float var = Q * (1.f / 128.f) - mean * mean;
            float rstd = rsqrtf(var + 1e-5f);
#pragma unroll
            for (int nj = 0; nj < 4; ++nj) {
                int gn = wn + nj * 16 + l15;
                float v = acc[mi][nj][rr];
                tok[(size_t)gm * 128 + gn] = v;
                float o = (v - mean) * rstd * wl[nj] + bl[nj];
                lnout[(size_t)gm * 128 + gn] = (short)f2b(o);
            }
        }
}

// ---------------------------------------------------------------------------
// proj GEMM + residual + LN(ffn) epilogue (r19 verbatim, PROVEN).
// ---------------------------------------------------------------------------
__global__ __launch_bounds__(256) void pmln_k(const short* __restrict__ A,
                                              const short* __restrict__ W,
                                              const float* __restrict__ lnw,
                                              const float* __restrict__ lnb,
                                              float* __restrict__ tok,
                                              short* __restrict__ lnout) {
    const int K = 128;
    __shared__ __align__(16) short As[2][64 * 40];
    __shared__ __align__(16) short Bs[2][128 * 40];
    __shared__ float lnbuf[64][2][2];
    const int tid = threadIdx.x;
    const int bm = blockIdx.x * 64;
    const int w = tid >> 6, lane = tid & 63;
    const int h = lane >> 4, l15 = lane & 15;
    const int wr = w >> 1, wc = w & 1;
    const int wm = wr * 32, wn = wc * 64;

    const int rowA = tid >> 2, c4 = tid & 3;
    const int rowB1 = rowA + 64;

    f32x4 acc[2][4];
#pragma unroll
    for (int i = 0; i < 2; ++i)
#pragma unroll
        for (int j = 0; j < 4; ++j) acc[i][j] = (f32x4){0.f, 0.f, 0.f, 0.f};

    auto ldA = [&](int k0, short* tmp) {
        const short* ap = A + (size_t)(bm + rowA) * K + k0 + c4 * 8;
        i32x2 a = *(const i32x2*)ap;
        i32x2 b = *(const i32x2*)(ap + 4);
        *(i32x2*)&tmp[0] = a; *(i32x2*)&tmp[4] = b;
    };
    auto ldW = [&](int row, int k0, short* tmp) {
        const short* wp = W + (size_t)row * K + k0 + c4 * 8;
        i32x2 a = *(const i32x2*)wp;
        i32x2 b = *(const i32x2*)(wp + 4);
        *(i32x2*)&tmp[0] = a; *(i32x2*)&tmp[4] = b;
    };
    auto compute = [&](int ph) {
        bf16x8 af[2], bf[4];
#pragma unroll
        for (int mi = 0; mi < 2; ++mi) af[mi] = *(const bf16x8*)&As[ph][(wm + mi * 16 + l15) * 40 + h * 8];
#pragma unroll
        for (int nj = 0; nj < 4; ++nj) bf[nj] = *(const bf16x8*)&Bs[ph][(wn + nj * 16 + l15) * 40 + h * 8];
#pragma unroll
        for (int mi = 0; mi < 2; ++mi)
#pragma unroll
            for (int nj = 0; nj < 4; ++nj)
                acc[mi][nj] = __builtin_amdgcn_mfma_f32_16x16x32_bf16(af[mi], bf[nj], acc[mi][nj], 0, 0, 0);
    };

    short aA[8], b0A[8], b1A[8];
    short aB[8], b0B[8], b1B[8];
    ldA(0, aA);  ldW(rowA, 0, b0A);  ldW(rowB1, 0, b1A);
    ldA(32, aB); ldW(rowA, 32, b0B); ldW(rowB1, 32, b1B);

    for (int k0 = 0; k0 < K; k0 += 64) {
        *(i32x4*)&As[0][rowA * 40 + c4 * 8]  = *(i32x4*)aA;
        *(i32x4*)&Bs[0][rowA * 40 + c4 * 8]  = *(i32x4*)b0A;
        *(i32x4*)&Bs[0][rowB1 * 40 + c4 * 8] = *(i32x4*)b1A;
        if (k0 + 64 < K) { ldA(k0 + 64, aA); ldW(rowA, k0 + 64, b0A); ldW(rowB1, k0 + 64, b1A); }
        __syncthreads();
        compute(0);
        *(i32x4*)&As[1][rowA * 40 + c4 * 8]  = *(i32x4*)aB;
        *(i32x4*)&Bs[1][rowA * 40 + c4 * 8]  = *(i32x4*)b0B;
        *(i32x4*)&Bs[1][rowB1 * 40 + c4 * 8] = *(i32x4*)b1B;
        if (k0 + 96 < K) { ldA(k0 + 96, aB); ldW(rowA, k0 + 96, b0B); ldW(rowB1, k0 + 96, b1B); }
        __syncthreads();
        compute(1);
    }

#pragma unroll
    for (int mi = 0; mi < 2; ++mi)
#pragma unroll
        for (int rr = 0; rr < 4; ++rr) {
            int gm = bm + wm + mi * 16 + h * 4 + rr;
#pragma unroll
            for (int nj = 0; nj < 4; ++nj) {
                int gn = wn + nj * 16 + l15;
                acc[mi][nj][rr] += tok[(size_t)gm * 128 + gn];
            }
        }
#pragma unroll
    for (int mi = 0; mi < 2; ++mi)
#pragma unroll
        for (int rr = 0; rr < 4; ++rr) {
            float s = 0.f, q = 0.f;
#pragma unroll
            for (int nj = 0; nj < 4; ++nj) {
                float v = acc[mi][nj][rr];
                s += v; q += v * v;
            }
#pragma unroll
            for (int off = 1; off < 16; off <<= 1) {
                s += __shfl_xor(s, off);
                q += __shfl_xor(q, off);
            }
            if (l15 == 0) {
                int rl = wm + mi * 16 + h * 4 + rr;
                lnbuf[rl][wc][0] = s;
                lnbuf[rl][wc][1] = q;
            }
        }
    __syncthreads();

    float wl[4], bl[4];
#pragma unroll
    for (int nj = 0; nj < 4; ++nj) {
        int gn = wn + nj * 16 + l15;
        wl[nj] = lnw[gn];
        bl[nj] = lnb[gn];
    }
#pragma unroll
    for (int mi = 0; mi < 2; ++mi)
#pragma unroll
        for (int rr = 0; rr < 4; ++rr) {
            int rl = wm + mi * 16 + h * 4 + rr;
            int gm = bm + rl;
            float S = lnbuf[rl][0][0] + lnbuf[rl][1][0];
            float Q = lnbuf[rl][0][1] + lnbuf[rl][1][1];
            float mean = S * (1.f / 128.f);
            float var = Q * (1.f / 128.f) - mean * mean;
            float rstd = rsqrtf(var + 1e-5f);
#pragma unroll
            for (int nj = 0; nj < 4; ++nj) {
                int gn = wn + nj * 16 + l15;
                float v = acc[mi][nj][rr];
                tok[(size_t)gm * 128 + gn] = v;
                float o = (v - mean) * rstd * wl[nj] + bl[nj];
                lnout[(size_t)gm * 128 + gn] = (short)f2b(o);
            }
        }
}

// ---------------------------------------------------------------------------
// NEW: ffn_out GEMM (K=352) + residual + Token2SAI fused.
// Phase 1 (mm64/r11 structure, 64x128 tile): acc = G @ ffnOutW^T + tok.
// Stage tok_new bf16 into LDS Tbf[64][136]; Phase 2: out = p3d @ tok_new^T
// (TROUT), p3dW fragments direct from L2-resident global. tok never written.
// ---------------------------------------------------------------------------
__global__ __launch_bounds__(256) void fmt2s_k(const short* __restrict__ G,
                                               const short* __restrict__ Wf,
                                               const short* __restrict__ Wp,
                                               const float* __restrict__ tok,
                                               float* __restrict__ outp) {
    const int K = 352;
    __shared__ __align__(16) short As[2][64 * 40];
    __shared__ __align__(16) short Bs[2][128 * 40];
    __shared__ __align__(16) short Tbf[64][136];
    const int tid = threadIdx.x;
    const int bm = blockIdx.x * 64;
    const int w = tid >> 6, lane = tid & 63;
    const int h = lane >> 4, l15 = lane & 15;
    const int wr = w >> 1, wc = w & 1;
    const int wm = wr * 32, wn = wc * 64;

    const int rowA = tid >> 2, c4 = tid & 3;
    const int rowB1 = rowA + 64;

    f32x4 acc[2][4];
#pragma unroll
    for (int i = 0; i < 2; ++i)
#pragma unroll
        for (int j = 0; j < 4; ++j) acc[i][j] = (f32x4){0.f, 0.f, 0.f, 0.f};

    short av[8], b0[8], b1[8];

    auto ldA = [&](int k0, short* tmp) {
        const short* ap = G + (size_t)(bm + rowA) * K + k0 + c4 * 8;
        i32x2 a = *(const i32x2*)ap;
        i32x2 b = *(const i32x2*)(ap + 4);
        *(i32x2*)&tmp[0] = a; *(i32x2*)&tmp[4] = b;
    };
    auto ldW = [&](int row, int k0, short* tmp) {
        const short* wp = Wf + (size_t)row * K + k0 + c4 * 8;
        i32x2 a = *(const i32x2*)wp;
        i32x2 b = *(const i32x2*)(wp + 4);
        *(i32x2*)&tmp[0] = a; *(i32x2*)&tmp[4] = b;
    };

    ldA(0, av);
    ldW(rowA, 0, b0);
    ldW(rowB1, 0, b1);

    int ph = 0;
    for (int k0 = 0; k0 < K; k0 += 32, ph ^= 1) {
        *(i32x4*)&As[ph][rowA * 40 + c4 * 8]  = *(i32x4*)av;
        *(i32x4*)&Bs[ph][rowA * 40 + c4 * 8]  = *(i32x4*)b0;
        *(i32x4*)&Bs[ph][rowB1 * 40 + c4 * 8] = *(i32x4*)b1;
        if (k0 + 32 < K) {
            ldA(k0 + 32, av);
            ldW(rowA, k0 + 32, b0);
            ldW(rowB1, k0 + 32, b1);
        }
        __syncthreads();

        bf16x8 af[2], bf[4];
#pragma unroll
        for (int mi = 0; mi < 2; ++mi) af[mi] = *(const bf16x8*)&As[ph][(wm + mi * 16 + l15) * 40 + h * 8];
#pragma unroll
        for (int nj = 0; nj < 4; ++nj) bf[nj] = *(const bf16x8*)&Bs[ph][(wn + nj * 16 + l15) * 40 + h * 8];
#pragma unroll
        for (int mi = 0; mi < 2; ++mi)
#pragma unroll
            for (int nj = 0; nj < 4; ++nj)
                acc[mi][nj] = __builtin_amdgcn_mfma_f32_16x16x32_bf16(af[mi], bf[nj], acc[mi][nj], 0, 0, 0);
    }

    // residual + stage tok_new (bf16) into LDS
    __syncthreads();   // all phase-1 LDS reads done before Tbf reuse-in-spirit
#pragma unroll
    for (int mi = 0; mi < 2; ++mi)
#pragma unroll
        for (int rr = 0; rr < 4; ++rr) {
            int rl = wm + mi * 16 + h * 4 + rr;
            int gm = bm + rl;
#pragma unroll
            for (int nj = 0; nj < 4; ++nj) {
                int gn = wn + nj * 16 + l15;
                float v = acc[mi][nj][rr] + tok[(size_t)gm * 128 + gn];
                Tbf[rl][gn] = (short)f2b(v);
            }
        }
    __syncthreads();

    // Phase 2: out[o][t] = sum_d p3d[o][d] * tok_new[t][d]; wave: 32 tok x 32 o
    f32x4 acc2[2][2];
#pragma unroll
    for (int i = 0; i < 2; ++i)
#pragma unroll
        for (int j = 0; j < 2; ++j) acc2[i][j] = (f32x4){0.f, 0.f, 0.f, 0.f};

#pragma unroll
    for (int ks = 0; ks < 4; ++ks) {
        bf16x8 af2[2], bf2[2];
#pragma unroll
        for (int mi = 0; mi < 2; ++mi)
            af2[mi] = *(const bf16x8*)&Tbf[wm + mi * 16 + l15][ks * 32 + h * 8];
#pragma unroll
        for (int nj = 0; nj < 2; ++nj) {
            int o = wc * 32 + nj * 16 + l15;
            bf2[nj] = *(const bf16x8*)(Wp + (size_t)o * 128 + ks * 32 + h * 8);
        }
#pragma unroll
        for (int mi = 0; mi < 2; ++mi)
#pragma unroll
            for (int nj = 0; nj < 2; ++nj)
                acc2[mi][nj] = __builtin_amdgcn_mfma_f32_16x16x32_bf16(bf2[nj], af2[mi], acc2[mi][nj], 0, 0, 0);
    }

#pragma unroll
    for (int mi = 0; mi < 2; ++mi) {
        int gt = bm + wm + mi * 16 + l15;
#pragma unroll
        for (int nj = 0; nj < 2; ++nj)
#pragma unroll
            for (int r = 0; r < 4; ++r) {
                int o = wc * 32 + nj * 16 + h * 4 + r;
                outp[(size_t)o * M_TOK + gt] = acc2[mi][nj][r];
            }
    }
}

// ---------------------------------------------------------------------------
// bf16 MFMA GEMM WIDE (r15 verbatim): 128x128 tile + 2-deep prefetch.
// ---------------------------------------------------------------------------
__global__ __launch_bounds__(256) void mmw_k(const short* __restrict__ A,
                                             const short* __restrict__ W,
                                             short* __restrict__ outp,
                                             int M, int N, int K) {
    __shared__ __align__(16) short As[2][128 * 40];
    __shared__ __align__(16) short Bs[2][128 * 40];
    const int tid = threadIdx.x;
    const int bm = blockIdx.x * 128;
    const int bn = blockIdx.y * 128;
    const int w = tid >> 6, lane = tid & 63;
    const int h = lane >> 4, l15 = lane & 15;
    const int wm = (w >> 1) * 64, wn = (w & 1) * 64;

    const int row0 = tid >> 2, c4 = tid & 3;
    const int row1 = row0 + 64;

    f32x4 acc[4][4];
#pragma unroll
    for (int i = 0; i < 4; ++i)
#pragma unroll
        for (int j = 0; j < 4; ++j) acc[i][j] = (f32x4){0.f, 0.f, 0.f, 0.f};

    auto ldA = [&](int row, int k0, short* tmp) {
        const short* ap = A + (size_t)(bm + row) * K + k0 + c4 * 8;
        i32x2 x = *(const i32x2*)ap;
        i32x2 y = *(const i32x2*)(ap + 4);
        *(i32x2*)&tmp[0] = x; *(i32x2*)&tmp[4] = y;
    };
    auto ldW = [&](int row, int k0, short* tmp) {
        int gn = bn + row;
        if (gn < N) {
            const short* wp = W + (size_t)gn * K + k0 + c4 * 8;
            i32x2 x = *(const i32x2*)wp;
            i32x2 y = *(const i32x2*)(wp + 4);
            *(i32x2*)&tmp[0] = x; *(i32x2*)&tmp[4] = y;
        } else {
#pragma unroll
            for (int i = 0; i < 8; ++i) tmp[i] = 0;
        }
    };
    auto compute = [&](int ph) {
        bf16x8 af[4], bf[4];
#pragma unroll
        for (int mi = 0; mi < 4; ++mi) af[mi] = *(const bf16x8*)&As[ph][(wm + mi * 16 + l15) * 40 + h * 8];
#pragma unroll
        for (int nj = 0; nj < 4; ++nj) bf[nj] = *(const bf16x8*)&Bs[ph][(wn + nj * 16 + l15) * 40 + h * 8];
#pragma unroll
        for (int mi = 0; mi < 4; ++mi)
#pragma unroll
            for (int nj = 0; nj < 4; ++nj)
                acc[mi][nj] = __builtin_amdgcn_mfma_f32_16x16x32_bf16(af[mi], bf[nj], acc[mi][nj], 0, 0, 0);
    };

    short a0A[8], a1A[8], b0A[8], b1A[8];
    short a0B[8], a1B[8], b0B[8], b1B[8];
    ldA(row0, 0, a0A);  ldA(row1, 0, a1A);  ldW(row0, 0, b0A);  ldW(row1, 0, b1A);
    ldA(row0, 32, a0B); ldA(row1, 32, a1B); ldW(row0, 32, b0B); ldW(row1, 32, b1B);

    for (int k0 = 0; k0 < K; k0 += 64) {
        *(i32x4*)&As[0][row0 * 40 + c4 * 8] = *(i32x4*)a0A;
        *(i32x4*)&As[0][row1 * 40 + c4 * 8] = *(i32x4*)a1A;
        *(i32x4*)&Bs[0][row0 * 40 + c4 * 8] = *(i32x4*)b0A;
        *(i32x4*)&Bs[0][row1 * 40 + c4 * 8] = *(i32x4*)b1A;
        if (k0 + 64 < K) {
            ldA(row0, k0 + 64, a0A); ldA(row1, k0 + 64, a1A);
            ldW(row0, k0 + 64, b0A); ldW(row1, k0 + 64, b1A);
        }
        __syncthreads();
        compute(0);
        *(i32x4*)&As[1][row0 * 40 + c4 * 8] = *(i32x4*)a0B;
        *(i32x4*)&As[1][row1 * 40 + c4 * 8] = *(i32x4*)a1B;
        *(i32x4*)&Bs[1][row0 * 40 + c4 * 8] = *(i32x4*)b0B;
        *(i32x4*)&Bs[1][row1 * 40 + c4 * 8] = *(i32x4*)b1B;
        if (k0 + 96 < K) {
            ldA(row0, k0 + 96, a0B); ldA(row1, k0 + 96, a1B);
            ldW(row0, k0 + 96, b0B); ldW(row1, k0 + 96, b1B);
        }
        __syncthreads();
        compute(1);
    }

#pragma unroll
    for (int mi = 0; mi < 4; ++mi) {
#pragma unroll
        for (int nj = 0; nj < 4; ++nj) {
            int gn = bn + wn + nj * 16 + l15;
            if (gn < N) {
#pragma unroll
                for (int r = 0; r < 4; ++r) {
                    int gm = bm + wm + mi * 16 + h * 4 + r;
                    outp[(size_t)gm * N + gn] = (short)f2b(acc[mi][nj][r]);
                }
            }
        }
    }
}

// ---------------------------------------------------------------------------
// Fused qkv depthwise 3x3 + l2norm(q,k) + temperature*log2e folded into q.
// ---------------------------------------------------------------------------
__global__ __launch_bounds__(256) void dwl2n_k(const short* __restrict__ in,
                                               const float* __restrict__ wqT,
                                               const float* __restrict__ temp,
                                               short* __restrict__ out) {
    int idx = blockIdx.x * 256 + threadIdx.x;    // < M*48
    int q = idx % 48;
    int t = idx / 48;
    int c0 = q * 8;
    int l = t & 1023, n = t >> 10;
    int y = l >> 5, x = l & 31;
    int tb = n << 10;

    float acc[8];
#pragma unroll
    for (int k = 0; k < 8; ++k) acc[k] = 0.f;

#pragma unroll
    for (int i = 0; i < 3; ++i) {
        int yy = y + i - 1;
        if (yy < 0 || yy >= 32) continue;
#pragma unroll
        for (int j = 0; j < 3; ++j) {
            int xx = x + j - 1;
            if (xx < 0 || xx >= 32) continue;
            bf16x8 d = *(const bf16x8*)(in + (size_t)(tb + (yy << 5) + xx) * 384 + c0);
            float4 wa = *(const float4*)(wqT + (i * 3 + j) * 384 + c0);
            float4 wb = *(const float4*)(wqT + (i * 3 + j) * 384 + c0 + 4);
            acc[0] += b2f((unsigned short)d[0]) * wa.x;
            acc[1] += b2f((unsigned short)d[1]) * wa.y;
            acc[2] += b2f((unsigned short)d[2]) * wa.z;
            acc[3] += b2f((unsigned short)d[3]) * wa.w;
            acc[4] += b2f((unsigned short)d[4]) * wb.x;
            acc[5] += b2f((unsigned short)d[5]) * wb.y;
            acc[6] += b2f((unsigned short)d[6]) * wb.z;
            acc[7] += b2f((unsigned short)d[7]) * wb.w;
        }
    }
    float ss = 0.f;
#pragma unroll
    for (int k = 0; k < 8; ++k) ss += acc[k] * acc[k];
    ss += __shfl_xor(ss, 1);
    ss += __shfl_xor(ss, 2);
    float sc;
    if (c0 < 128)       sc = (1.f / fmaxf(sqrtf(ss), 1e-12f)) * temp[c0 >> 5] * 1.44269504089f;
    else if (c0 < 256)  sc = 1.f / fmaxf(sqrtf(ss), 1e-12f);
    else                sc = 1.f;
    unsigned o[4];
#pragma unroll
    for (int k = 0; k < 4; ++k)
        o[k] = f2b(acc[2 * k] * sc) | ((unsigned)f2b(acc[2 * k + 1] * sc) << 16);
    *(i32x4*)(out + (size_t)t * 384 + c0) = *(i32x4*)o;
}

// ---------------------------------------------------------------------------
// Fused GDFN depthwise: dual 3x3 dwconv + exact gelu gate. out [M][352].
// ---------------------------------------------------------------------------
__global__ __launch_bounds__(256) void gdfn2_k(const short* __restrict__ in,
                                               const float* __restrict__ wgT,
                                               short* __restrict__ out) {
    int idx = blockIdx.x * 256 + threadIdx.x;    // < M*44
    int q = idx % 44;
    int t = idx / 44;
    int c0 = q * 8;
    short* op = out + (size_t)t * 352 + c0;
    if (q == 43) {
        *(i32x4*)op = (i32x4){0, 0, 0, 0};
        return;
    }
    int l = t & 1023, n = t >> 10;
    int y = l >> 5, x = l & 31;
    int tb = n << 10;

    float a[8], g[8];
#pragma unroll
    for (int k = 0; k < 8; ++k) { a[k] = 0.f; g[k] = 0.f; }

#pragma unroll
    for (int i = 0; i < 3; ++i) {
        int yy = y + i - 1;
        if (yy < 0 || yy >= 32) continue;
#pragma unroll
        for (int j = 0; j < 3; ++j) {
            int xx = x + j - 1;
            if (xx < 0 || xx >= 32) continue;
            const short* p = in + (size_t)(tb + (yy << 5) + xx) * 680 + c0;
            bf16x8 d1 = *(const bf16x8*)p;
            i32x2 d2a = *(const i32x2*)(p + 340);
            i32x2 d2b = *(const i32x2*)(p + 344);
            short d2[8];
            *(i32x2*)&d2[0] = d2a; *(i32x2*)&d2[4] = d2b;
            const float* wp = wgT + (i * 3 + j) * 680 + c0;
            float4 w1a = *(const float4*)wp;
            float4 w1b = *(const float4*)(wp + 4);
            float w1[8] = {w1a.x, w1a.y, w1a.z, w1a.w, w1b.x, w1b.y, w1b.z, w1b.w};
            float w2[8];
#pragma unroll
            for (int k = 0; k < 8; ++k) w2[k] = wp[340 + k];
#pragma unroll
            for (int k = 0; k < 8; ++k) {
                a[k] += b2f((unsigned short)d1[k]) * w1[k];
                g[k] += b2f((unsigned short)d2[k]) * w2[k];
            }
        }
    }
    unsigned o[4];
#pragma unroll
    for (int k = 0; k < 4; ++k) {
        float r0 = 0.5f * a[2 * k] * (1.f + erff(a[2 * k] * 0.70710678118f)) * g[2 * k];
        float r1 = 0.5f * a[2 * k + 1] * (1.f + erff(a[2 * k + 1] * 0.70710678118f)) * g[2 * k + 1];
        o[k] = f2b(r0) | ((unsigned)f2b(r1) << 16);
    }
    if (q == 42) { o[2] = 0; o[3] = 0; }
    *(i32x4*)op = *(i32x4*)o;
}

// ---------------------------------------------------------------------------
// MFMA flash attention v9 (r18 verbatim — PROVEN at ~43.5us).
// ---------------------------------------------------------------------------
__global__ __launch_bounds__(256) void attn_k(const short* __restrict__ qkv,
                                              short* __restrict__ outp) {
    __shared__ __align__(16) short Ks[2][64 * 40];
    __shared__ __align__(16) short Vp[2][2048];
    const int b = blockIdx.x;
    const int orig = (b & 7) * 200 + (b >> 3);   // XCD-contiguous remap
    const int qt = orig & 15, nh = orig >> 4;
    const int hd = nh & 3, n = nh >> 2;
    const int tid = threadIdx.x;
    const int w = tid >> 6, lane = tid & 63;
    const int h = lane >> 4, l15 = lane & 15;
    const size_t base = (size_t)n * 1024 * 384;
    const int qrow = qt * 64 + w * 16 + l15;

    bf16x8 qf = *(const bf16x8*)(qkv + base + (size_t)qrow * 384 + hd * 32 + h * 8);
    f32x4 o0 = {0.f,0.f,0.f,0.f}, o1 = {0.f,0.f,0.f,0.f};
    f32x4 osum = {0.f,0.f,0.f,0.f};
    union { unsigned u[4]; bf16x8 v; } ones;
#pragma unroll
    for (int r = 0; r < 4; ++r) ones.u[r] = 0x3F803F80u;

    const int skey = tid >> 2, sc4 = tid & 3;
    const int sg = skey >> 5, skey5 = skey & 31;
    const int sh = (skey5 >> 2) & 3;
    const int sj = (skey5 & 3) + ((skey5 >> 4) << 2);
    const int sgran0 = (sg * 4 + sh) * 32 + sc4 * 8;
    const short* kbase = qkv + base + (size_t)skey * 384 + 128 + hd * 32 + sc4 * 8;

    auto scatterV = [&](int nb, i32x4 vreg) {
        short vs[8];
        *(i32x4*)vs = vreg;
#pragma unroll
        for (int i = 0; i < 8; ++i) {
            int gran = sgran0 + i;
            gran ^= (gran >> 3) & 7;
            Vp[nb][gran * 8 + sj] = vs[i];
        }
    };
    auto compute = [&](int nb) {
        const bf16x8 kf0 = *(const bf16x8*)&Ks[nb][l15 * 40 + h * 8];
        const bf16x8 kf1 = *(const bf16x8*)&Ks[nb][(16 + l15) * 40 + h * 8];
        const bf16x8 kf2 = *(const bf16x8*)&Ks[nb][(32 + l15) * 40 + h * 8];
        const bf16x8 kf3 = *(const bf16x8*)&Ks[nb][(48 + l15) * 40 + h * 8];
        int gr0 = h * 32 + l15;            gr0 ^= (gr0 >> 3) & 7;
        int gr1 = h * 32 + 16 + l15;       gr1 ^= (gr1 >> 3) & 7;
        int gr2 = (4 + h) * 32 + l15;      gr2 ^= (gr2 >> 3) & 7;
        int gr3 = (4 + h) * 32 + 16 + l15; gr3 ^= (gr3 >> 3) & 7;
        const bf16x8 va0 = *(const bf16x8*)&Vp[nb][gr0 * 8];
        const bf16x8 va1 = *(const bf16x8*)&Vp[nb][gr1 * 8];
        const bf16x8 vb0 = *(const bf16x8*)&Vp[nb][gr2 * 8];
        const bf16x8 vb1 = *(const bf16x8*)&Vp[nb][gr3 * 8];
        const f32x4 z = {0.f, 0.f, 0.f, 0.f};

        __builtin_amdgcn_s_setprio(1);
        f32x4 s0 = __builtin_amdgcn_mfma_f32_16x16x32_bf16(kf0, qf, z, 0, 0, 0);
        f32x4 s1 = __builtin_amdgcn_mfma_f32_16x16x32_bf16(kf1, qf, z, 0, 0, 0);
        f32x4 s2 = __builtin_amdgcn_mfma_f32_16x16x32_bf16(kf2, qf, z, 0, 0, 0);
        f32x4 s3 = __builtin_amdgcn_mfma_f32_16x16x32_bf16(kf3, qf, z, 0, 0, 0);
        __builtin_amdgcn_s_setprio(0);
        float p[16];
#pragma unroll
        for (int r = 0; r < 4; ++r) {
            p[r]      = exp2f(s0[r]);
            p[4 + r]  = exp2f(s1[r]);
            p[8 + r]  = exp2f(s2[r]);
            p[12 + r] = exp2f(s3[r]);
        }
        union { unsigned u[4]; bf16x8 v; } pf1, pf2;
#pragma unroll
        for (int r = 0; r < 4; ++r) {
            pf1.u[r] = cvtpk(p[2 * r], p[2 * r + 1]);
            pf2.u[r] = cvtpk(p[8 + 2 * r], p[8 + 2 * r + 1]);
        }
        __builtin_amdgcn_s_setprio(1);
        osum = __builtin_amdgcn_mfma_f32_16x16x32_bf16(ones.v, pf1.v, osum, 0, 0, 0);
        osum = __builtin_amdgcn_mfma_f32_16x16x32_bf16(ones.v, pf2.v, osum, 0, 0, 0);
        o0 = __builtin_amdgcn_mfma_f32_16x16x32_bf16(va0, pf1.v, o0, 0, 0, 0);
        o1 = __builtin_amdgcn_mfma_f32_16x16x32_bf16(va1, pf1.v, o1, 0, 0, 0);
        o0 = __builtin_amdgcn_mfma_f32_16x16x32_bf16(vb0, pf2.v, o0, 0, 0, 0);
        o1 = __builtin_amdgcn_mfma_f32_16x16x32_bf16(vb1, pf2.v, o1, 0, 0, 0);
        __builtin_amdgcn_s_setprio(0);
    };

    i32x4 kregA = *(const i32x4*)kbase;
    i32x4 vregA = *(const i32x4*)(kbase + 128);
    i32x4 kregB = *(const i32x4*)(kbase + (size_t)64 * 384);
    i32x4 vregB = *(const i32x4*)(kbase + (size_t)64 * 384 + 128);

    for (int t = 0; t < 16; t += 2) {
        *(i32x4*)&Ks[0][skey * 40 + sc4 * 8] = kregA;
        scatterV(0, vregA);
        if (t + 2 < 16) {
            const short* kp = kbase + (size_t)(t + 2) * 64 * 384;
            kregA = *(const i32x4*)kp;
            vregA = *(const i32x4*)(kp + 128);
        }
        __syncthreads();
        compute(0);
        *(i32x4*)&Ks[1][skey * 40 + sc4 * 8] = kregB;
        scatterV(1, vregB);
        if (t + 3 < 16) {
            const short* kp = kbase + (size_t)(t + 3) * 64 * 384;
            kregB = *(const i32x4*)kp;
            vregB = *(const i32x4*)(kp + 128);
        }
        __syncthreads();
        compute(1);
    }

    float inv = 1.f / osum[0];

    size_t ob = ((size_t)n * 1024 + qrow) * 128 + hd * 32;
    unsigned u;
    u = f2b(o0[0] * inv) | ((unsigned)f2b(o0[1] * inv) << 16); *(unsigned*)(outp + ob + h * 4) = u;
    u = f2b(o0[2] * inv) | ((unsigned)f2b(o0[3] * inv) << 16); *(unsigned*)(outp + ob + h * 4 + 2) = u;
    u = f2b(o1[0] * inv) | ((unsigned)f2b(o1[1] * inv) << 16); *(unsigned*)(outp + ob + 16 + h * 4) = u;
    u = f2b(o1[2] * inv) | ((unsigned)f2b(o1[3] * inv) << 16); *(unsigned*)(outp + ob + 16 + h * 4 + 2) = u;
}

// ---------------------------------------------------------------------------
extern "C" void kernel_launch(void* const* d_in, const int* in_sizes, int n_in,
                              void* d_out, int out_size, void* d_ws, size_t ws_size,
                              hipStream_t stream) {
    const float* buffer      = (const float*)d_in[0];
    const float* mlp_w       = (const float*)d_in[1];
    const float* ln_attn_w   = (const float*)d_in[2];
    const float* ln_attn_b   = (const float*)d_in[3];
    const float* ln_ffn_w    = (const float*)d_in[4];
    const float* ln_ffn_b    = (const float*)d_in[5];
    const float* qkv_w       = (const float*)d_in[6];
    const float* qkv_dw_w    = (const float*)d_in[7];
    const float* temperature = (const float*)d_in[8];
    const float* proj_attn_w = (const float*)d_in[9];
    const float* ffn_in_w    = (const float*)d_in[10];
    const float* ffn_dw_w    = (const float*)d_in[11];
    const float* ffn_out_w   = (const float*)d_in[12];
    const float* proj3d_w    = (const float*)d_in[13];

    char* wsb = (char*)d_ws;
    short* Wbf     = (short*)wsb;                 // 287744 bf16 weights
    short* mlpW    = Wbf;                         // [128][640] tap-major
    short* qkvW    = Wbf + 81920;                 // [384][128]
    short* projW   = Wbf + 131072;                // [128][128]
    short* ffnInW  = Wbf + 147456;                // [680][128]
    short* ffnOutW = Wbf + 234496;                // [128][352] (padded)
    short* p3dW    = Wbf + 279552;                // [64][128]
    float* wqT     = (float*)(wsb + 575488);      // [9][384] f32
    float* wgT     = (float*)(wsb + 589312);      // [9][680] f32
    float* tok     = (float*)(wsb + 33381792);    // [M][128] f32
    short* LNbf    = (short*)(wsb + 46488992);    // [M][128] bf16
    short* QKVpre  = (short*)(wsb + 53042592);    // [M][384] bf16
    short* qkvb    = (short*)(wsb + 72703392);    // [M][384] bf16
    short* AObf    = (short*)(wsb + 92364192);    // [M][128] bf16
    short* F1      = (short*)(wsb + 98917792);    // [M][680] bf16
    short* G       = (short*)(wsb + 133733792);   // [M][352] bf16 (padded)

    dim3 blk(256);

    prep_k<<<1162, blk, 0, stream>>>(mlp_w, qkv_w, proj_attn_w, ffn_in_w, ffn_out_w, proj3d_w,
                                     qkv_dw_w, ffn_dw_w, Wbf, wqT, wgT);

    // S2T + LN(attn) fused: tok f32 + LNbf bf16 in one pass
    mmim_ln_k<<<400, blk, 0, stream>>>(buffer, mlpW, ln_attn_w, ln_attn_b, tok, LNbf);
    // qkv 1x1 (bf16 out) — WIDE tile, 2-deep prefetch
    mmw_k<<<dim3(200, 3), blk, 0, stream>>>(LNbf, qkvW, QKVpre, M_TOK, 384, 128);
    // fused dwconv + l2norm + temperature fold
    dwl2n_k<<<4800, blk, 0, stream>>>(QKVpre, wqT, temperature, qkvb);
    // attention v9
    attn_k<<<1600, blk, 0, stream>>>(qkvb, AObf);
    // proj + residual + LN(ffn) fused: updates tok, writes LNbf
    pmln_k<<<400, blk, 0, stream>>>(AObf, projW, ln_ffn_w, ln_ffn_b, tok, LNbf);
    // ffn_in 1x1 (bf16 out) — WIDE tile, 2-deep prefetch
    mmw_k<<<dim3(200, 6), blk, 0, stream>>>(LNbf, ffnInW, F1, M_TOK, 680, 128);
    // fused GDFN dwconv + gelu gate -> G [M][352] (padded)
    gdfn2_k<<<4400, blk, 0, stream>>>(F1, wgT, G);
    // ffn_out + residual + Token2SAI fused (writes d_out directly)
    fmt2s_k<<<400, blk, 0, stream>>>(G, ffnOutW, p3dW, tok, (float*)d_out);
}